// Round 1
// baseline (922.942 us; speedup 1.0000x reference)
//
#include <hip/hip_runtime.h>
#include <math.h>

#define BB 32
#define NN 1024
#define FF 10
#define DD 64
#define MM 4
#define RR 8
#define KK 20
#define BNROWS (BB*NN)   // 32768

// ---- workspace layout (float offsets) ----
#define OFF_HIT   0ull           // h_it   [B,N,D]  2097152
#define OFF_XLIN  2097152ull     // x_lin  [B,N,D]  2097152
#define OFF_EIT   4194304ull     // e_it   [B,N]    32768
#define OFF_PIT   4227072ull     // pi_t   [B,M]    128
#define OFF_MIXED 4227200ull     // mixed  [B,N,D]  2097152
#define OFF_SI    6324352ull     // s_i    [B,N]    32768
#define OFF_SJ    6357120ull     // s_j    [B,N]    32768
#define OFF_TKV   6389888ull     // topk_vals [B,N,K] 655360
#define OFF_TKI   7045248ull     // topk_idx  [B,N,K] 655360 (ints)
#define OFF_GNN   7700608ull     // gnn_pre [B,N,D] 2097152
#define OFF_OUTP  9797760ull     // out_pre [B,N,D] 2097152
#define OFF_STAT  11894912ull    // stats: bn1_sum/sq (128) + bno_sum/sq (128)

__device__ __forceinline__ float wave_sum(float v) {
    #pragma unroll
    for (int off = 32; off; off >>= 1) v += __shfl_xor(v, off);
    return v;
}
__device__ __forceinline__ float wave_max(float v) {
    #pragma unroll
    for (int off = 32; off; off >>= 1) v = fmaxf(v, __shfl_xor(v, off));
    return v;
}

// ---------------- K0: zero stats ----------------
__global__ void k_zero(float* p) { p[threadIdx.x] = 0.f; }

// ---------------- K1a: per-row h_it, x_lin, e_it ----------------
__global__ __launch_bounds__(256) void k_rows(
    const float* __restrict__ data, const float* __restrict__ W_cond,
    const float* __restrict__ b_cond, const float* __restrict__ W_ap,
    const float* __restrict__ b_ap, const float* __restrict__ W_av,
    const float* __restrict__ W_gnn,
    float* __restrict__ h_it, float* __restrict__ x_lin, float* __restrict__ e_it)
{
    int w = threadIdx.x >> 6, lane = threadIdx.x & 63;
    int r = blockIdx.x * 4 + w;               // row in [0, B*N)
    const float* dr = data + r * FF;
    float df[FF];
    #pragma unroll
    for (int f = 0; f < FF; f++) df[f] = dr[f];
    float h = b_cond[lane], x = 0.f;
    #pragma unroll
    for (int f = 0; f < FF; f++) {
        h = fmaf(df[f], W_cond[f * DD + lane], h);
        x = fmaf(df[f], W_gnn[f * DD + lane], x);
    }
    h_it[r * DD + lane] = h;
    x_lin[r * DD + lane] = x;
    // ah[d] = leaky(h . W_ap[:,d] + b_ap[d]); e = sum_d ah[d]*W_av[d]
    float acc = b_ap[lane];
    #pragma unroll
    for (int e2 = 0; e2 < DD; e2++)
        acc = fmaf(__shfl(h, e2), W_ap[e2 * DD + lane], acc);
    float lr = acc > 0.f ? acc : 0.2f * acc;
    float ep = wave_sum(lr * W_av[lane]);
    if (lane == 0) e_it[r] = ep;
}

// ---------------- K1b: per-b softmax over N + weighted pool ----------------
__global__ __launch_bounds__(256) void k_pool(
    const float* __restrict__ e_it, const float* __restrict__ h_it,
    float* __restrict__ h_sys)
{
    int b = blockIdx.x, t = threadIdx.x, w = t >> 6, lane = t & 63;
    __shared__ float sbeta[NN];
    __shared__ float red[4];
    __shared__ float part[4][DD];
    float v[4]; float mx = -INFINITY;
    #pragma unroll
    for (int i = 0; i < 4; i++) { v[i] = e_it[b * NN + t + i * 256]; mx = fmaxf(mx, v[i]); }
    mx = wave_max(mx);
    if (lane == 0) red[w] = mx;
    __syncthreads();
    mx = fmaxf(fmaxf(red[0], red[1]), fmaxf(red[2], red[3]));
    float s = 0.f;
    #pragma unroll
    for (int i = 0; i < 4; i++) { v[i] = expf(v[i] - mx); s += v[i]; }
    s = wave_sum(s);
    __syncthreads();
    if (lane == 0) red[w] = s;
    __syncthreads();
    s = red[0] + red[1] + red[2] + red[3];
    #pragma unroll
    for (int i = 0; i < 4; i++) sbeta[t + i * 256] = v[i] / s;
    __syncthreads();
    float acc = 0.f;
    for (int n = w * 256; n < w * 256 + 256; n++)
        acc = fmaf(sbeta[n], h_it[(b * NN + n) * DD + lane], acc);
    part[w][lane] = acc;
    __syncthreads();
    if (w == 0)
        h_sys[b * DD + lane] = part[0][lane] + part[1][lane] + part[2][lane] + part[3][lane];
}

// ---------------- K2: routing (gumbel top-2 straight-through) ----------------
__global__ void k_route(const float* __restrict__ h_sys, const float* __restrict__ W_r,
                        const float* __restrict__ b_r, const float* __restrict__ gumbel,
                        float* __restrict__ pi_soft, float* __restrict__ pi_t)
{
    int b = threadIdx.x;
    if (b >= BB) return;
    float lg[MM];
    #pragma unroll
    for (int m = 0; m < MM; m++) {
        float a = b_r[m] + gumbel[b * MM + m];
        for (int d = 0; d < DD; d++) a = fmaf(h_sys[b * DD + d], W_r[d * MM + m], a);
        lg[m] = a;
    }
    float mx = fmaxf(fmaxf(lg[0], lg[1]), fmaxf(lg[2], lg[3]));
    float s = 0.f, p[MM];
    #pragma unroll
    for (int m = 0; m < MM; m++) { p[m] = expf(lg[m] - mx); s += p[m]; }
    #pragma unroll
    for (int m = 0; m < MM; m++) { p[m] /= s; pi_soft[b * MM + m] = p[m]; }
    int i1 = 0; float v1 = p[0];
    #pragma unroll
    for (int m = 1; m < MM; m++) if (p[m] > v1) { v1 = p[m]; i1 = m; }
    int i2 = -1; float v2 = -1.f;
    #pragma unroll
    for (int m = 0; m < MM; m++) if (m != i1 && p[m] > v2) { v2 = p[m]; i2 = m; }
    float norm = fmaxf(v1 + v2, 1e-12f);
    #pragma unroll
    for (int m = 0; m < MM; m++)
        pi_t[b * MM + m] = (m == i1 ? v1 : (m == i2 ? v2 : 0.f)) / norm;
}

// ---------------- K3: mixed embeddings + s_i/s_j ----------------
__global__ __launch_bounds__(256) void k_mixed(
    const float* __restrict__ e_base, const float* __restrict__ lr_u,
    const float* __restrict__ lr_v, const float* __restrict__ pi_t,
    const float* __restrict__ x_lin,
    const float* __restrict__ att_i, const float* __restrict__ att_j,
    const float* __restrict__ att_em_i, const float* __restrict__ att_em_j,
    float* __restrict__ mixed, float* __restrict__ s_i, float* __restrict__ s_j)
{
    int w = threadIdx.x >> 6, lane = threadIdx.x & 63;
    int n = blockIdx.x * 4 + w;
    float LR[MM];
    #pragma unroll
    for (int m = 0; m < MM; m++) {
        float a = 0.f;
        #pragma unroll
        for (int r = 0; r < RR; r++)
            a = fmaf(lr_u[(m * NN + n) * RR + r], lr_v[(m * RR + r) * DD + lane], a);
        LR[m] = a;
    }
    float eb = e_base[n * DD + lane];
    float ai = att_i[lane], aj = att_j[lane], aei = att_em_i[lane], aej = att_em_j[lane];
    for (int b = 0; b < BB; b++) {
        float mx = 0.f;
        #pragma unroll
        for (int m = 0; m < MM; m++) mx = fmaf(pi_t[b * MM + m], eb + LR[m], mx);
        mixed[(b * NN + n) * DD + lane] = mx;
        float x = x_lin[(b * NN + n) * DD + lane];
        float r1 = wave_sum(x * ai + mx * aei);
        float r2 = wave_sum(x * aj + mx * aej);
        if (lane == 0) { s_i[b * NN + n] = r1; s_j[b * NN + n] = r2; }
    }
}

// ---------------- K4: fused scores + top-20 ----------------
__global__ __launch_bounds__(256) void k_topk(
    const float* __restrict__ mixed, float* __restrict__ tkv, int* __restrict__ tki)
{
    __shared__ float tile[DD * 130];
    int t = threadIdx.x, w = t >> 6, lane = t & 63;
    int xcd = blockIdx.x & 7;
    int g = blockIdx.x >> 3;            // 0..511
    int b = xcd + 8 * (g >> 7);         // group same-b blocks on one XCD
    int rblk = g & 127;                 // rows rblk*8 .. +8 within b
    int i0 = rblk * 8 + w * 2;          // this wave's two local rows
    const float* mb = mixed + (size_t)b * NN * DD;

    float mi0[DD], mi1[DD];
    #pragma unroll
    for (int d = 0; d < DD; d++) { mi0[d] = mb[i0 * DD + d]; mi1[d] = mb[(i0 + 1) * DD + d]; }

    float sc[2][16];
    for (int jt = 0; jt < 8; jt++) {
        __syncthreads();
        // stage 128 j-rows transposed: tile[d][jj], stride 130
        #pragma unroll
        for (int c = 0; c < 8; c++) {
            int id = t + c * 256;            // 0..2047 float4 elements
            int jj = id >> 4, dq = id & 15;
            const float4 v4 = *(const float4*)(mb + (size_t)(jt * 128 + jj) * DD + dq * 4);
            tile[(dq * 4 + 0) * 130 + jj] = v4.x;
            tile[(dq * 4 + 1) * 130 + jj] = v4.y;
            tile[(dq * 4 + 2) * 130 + jj] = v4.z;
            tile[(dq * 4 + 3) * 130 + jj] = v4.w;
        }
        __syncthreads();
        float a00 = 0.f, a01 = 0.f, a10 = 0.f, a11 = 0.f;
        #pragma unroll
        for (int d = 0; d < DD; d++) {
            float2 tj = *(const float2*)&tile[d * 130 + 2 * lane];
            a00 = fmaf(mi0[d], tj.x, a00);
            a01 = fmaf(mi0[d], tj.y, a01);
            a10 = fmaf(mi1[d], tj.x, a10);
            a11 = fmaf(mi1[d], tj.y, a11);
        }
        sc[0][jt * 2] = a00; sc[0][jt * 2 + 1] = a01;
        sc[1][jt * 2] = a10; sc[1][jt * 2 + 1] = a11;
    }

    // selection: slot s of lane l -> j = (s>>1)*128 + 2*l + (s&1)
    #pragma unroll
    for (int rr = 0; rr < 2; rr++) {
        int irow = b * NN + i0 + rr;
        float bv = sc[rr][0]; int bs = 0;
        #pragma unroll
        for (int i = 1; i < 16; i++) if (sc[rr][i] > bv) { bv = sc[rr][i]; bs = i; }
        float myv = 0.f; int myj = 0;
        for (int k = 0; k < KK; k++) {
            float m = wave_max(bv);
            unsigned long long ball = __ballot(bv == m);
            int winner = (int)__builtin_ctzll(ball);
            int wslot = __shfl(bs, winner);
            int j = (wslot >> 1) * 128 + 2 * winner + (wslot & 1);
            if (lane == k) { myv = m; myj = j; }
            bool win = (lane == winner);
            #pragma unroll
            for (int i = 0; i < 16; i++)
                if (win && i == wslot) sc[rr][i] = -INFINITY;
            if (win) {
                bv = sc[rr][0]; bs = 0;
                #pragma unroll
                for (int i = 1; i < 16; i++) if (sc[rr][i] > bv) { bv = sc[rr][i]; bs = i; }
            }
        }
        if (lane < KK) { tkv[irow * KK + lane] = myv; tki[irow * KK + lane] = myj; }
    }
}

// ---------------- K5: GAT attention + aggregation ----------------
__global__ __launch_bounds__(256) void k_gat(
    const float* __restrict__ x_lin, const float* __restrict__ s_i,
    const float* __restrict__ s_j, const float* __restrict__ tkv,
    const int* __restrict__ tki, const float* __restrict__ b_gnn,
    float* __restrict__ gnn_pre)
{
    int w = threadIdx.x >> 6, lane = threadIdx.x & 63;
    int r = blockIdx.x * 4 + w;
    int b = r >> 10, n = r & 1023;
    float vk = -INFINITY; int ik = 0;
    if (lane < KK) { vk = tkv[r * KK + lane]; ik = tki[r * KK + lane]; }
    // topk_w = softmax over 20 vals
    float m1 = wave_max(vk);
    float ek = (lane < KK) ? expf(vk - m1) : 0.f;
    float s1v = wave_sum(ek);
    float wk = ek / s1v;
    // alphas
    float si = s_i[r], sjn = s_j[r];
    float a = -INFINITY;
    if (lane < KK) {
        float sjk = s_j[(b << 10) + ik];
        float t2 = si + sjk;
        a = (ik == n) ? -INFINITY : (t2 > 0.f ? t2 : 0.2f * t2);
    }
    float ts = si + sjn;
    float aself = ts > 0.f ? ts : 0.2f * ts;
    float am = wave_max(fmaxf(a, aself));
    float ea = (lane < KK && a != -INFINITY) ? expf(a - am) : 0.f;
    float es = expf(aself - am);
    float ssum = wave_sum(ea) + es;
    float wnb = (ea / ssum) * wk;
    float wself = es / ssum;
    // aggregate
    float acc = b_gnn[lane] + wself * x_lin[r * DD + lane];
    for (int k = 0; k < KK; k++) {
        int jk = __shfl(ik, k);
        float wv = __shfl(wnb, k);
        acc = fmaf(wv, x_lin[((b << 10) + jk) * DD + lane], acc);
    }
    gnn_pre[r * DD + lane] = acc;
}

// ---------------- K6: per-channel sum / sumsq ----------------
__global__ __launch_bounds__(256) void k_stats(const float* __restrict__ src, float* __restrict__ sums)
{
    int w = threadIdx.x >> 6, lane = threadIdx.x & 63;
    __shared__ float ps[4][DD], pq[4][DD];
    float s = 0.f, q = 0.f;
    int base = blockIdx.x * 512;
    for (int i = w; i < 512; i += 4) {
        float v = src[(size_t)(base + i) * DD + lane];
        s += v; q = fmaf(v, v, q);
    }
    ps[w][lane] = s; pq[w][lane] = q;
    __syncthreads();
    if (w == 0) {
        s = ps[0][lane] + ps[1][lane] + ps[2][lane] + ps[3][lane];
        q = pq[0][lane] + pq[1][lane] + pq[2][lane] + pq[3][lane];
        atomicAdd(&sums[lane], s);
        atomicAdd(&sums[DD + lane], q);
    }
}

// ---------------- K7: bn1 + relu + embed multiply ----------------
__global__ __launch_bounds__(256) void k_bn1(
    const float* __restrict__ gnn_pre, const float* __restrict__ stats,
    const float* __restrict__ gamma, const float* __restrict__ beta,
    const float* __restrict__ net, float* __restrict__ out_pre)
{
    int e = blockIdx.x * 256 + threadIdx.x;
    int d = e & 63, r = e >> 6, n = r & 1023;
    float mean = stats[d] * (1.0f / BNROWS);
    float var = stats[DD + d] * (1.0f / BNROWS) - mean * mean;
    float rs = rsqrtf(var + 1e-5f);
    float y = (gnn_pre[e] - mean) * rs * gamma[d] + beta[d];
    y = y > 0.f ? y : 0.f;
    out_pre[e] = y * net[n * DD + d];
}

// ---------------- K8: bn_out + relu + head ----------------
__global__ __launch_bounds__(256) void k_head(
    const float* __restrict__ out_pre, const float* __restrict__ stats,
    const float* __restrict__ gamma, const float* __restrict__ beta,
    const float* __restrict__ W_out, const float* __restrict__ b_out,
    float* __restrict__ out)
{
    int w = threadIdx.x >> 6, lane = threadIdx.x & 63;
    int r = blockIdx.x * 4 + w;
    float mean = stats[lane] * (1.0f / BNROWS);
    float var = stats[DD + lane] * (1.0f / BNROWS) - mean * mean;
    float rs = rsqrtf(var + 1e-5f);
    float y = (out_pre[(size_t)r * DD + lane] - mean) * rs * gamma[lane] + beta[lane];
    y = y > 0.f ? y : 0.f;
    float p = wave_sum(y * W_out[lane]);
    if (lane == 0) out[r] = p + b_out[0];
}

extern "C" void kernel_launch(void* const* d_in, const int* in_sizes, int n_in,
                              void* d_out, int out_size, void* d_ws, size_t ws_size,
                              hipStream_t stream)
{
    const float* data     = (const float*)d_in[0];
    const float* gumbel   = (const float*)d_in[1];
    const float* W_cond   = (const float*)d_in[2];
    const float* b_cond   = (const float*)d_in[3];
    const float* W_ap     = (const float*)d_in[4];
    const float* b_ap     = (const float*)d_in[5];
    const float* W_av     = (const float*)d_in[6];
    const float* W_r      = (const float*)d_in[7];
    const float* b_r      = (const float*)d_in[8];
    const float* e_base   = (const float*)d_in[9];
    const float* lr_u     = (const float*)d_in[10];
    const float* lr_v     = (const float*)d_in[11];
    const float* W_gnn    = (const float*)d_in[12];
    const float* att_i    = (const float*)d_in[13];
    const float* att_j    = (const float*)d_in[14];
    const float* att_em_i = (const float*)d_in[15];
    const float* att_em_j = (const float*)d_in[16];
    const float* b_gnn    = (const float*)d_in[17];
    const float* bn1_g    = (const float*)d_in[18];
    const float* bn1_b    = (const float*)d_in[19];
    const float* net      = (const float*)d_in[20];
    const float* bno_g    = (const float*)d_in[21];
    const float* bno_b    = (const float*)d_in[22];
    const float* W_out    = (const float*)d_in[23];
    const float* b_out    = (const float*)d_in[24];

    float* ws = (float*)d_ws;
    float* h_it   = ws + OFF_HIT;
    float* x_lin  = ws + OFF_XLIN;
    float* e_it   = ws + OFF_EIT;
    float* pi_t   = ws + OFF_PIT;
    float* mixed  = ws + OFF_MIXED;
    float* s_i    = ws + OFF_SI;
    float* s_j    = ws + OFF_SJ;
    float* tkv    = ws + OFF_TKV;
    int*   tki    = (int*)(ws + OFF_TKI);
    float* gnn_pre = ws + OFF_GNN;
    float* out_pre = ws + OFF_OUTP;
    float* stats   = ws + OFF_STAT;

    float* out0    = (float*)d_out;
    float* h_sys   = out0 + BB * NN;              // 32768
    float* pi_soft = out0 + BB * NN + BB * DD;    // 34816

    k_zero<<<1, 256, 0, stream>>>(stats);
    k_rows<<<BNROWS / 4, 256, 0, stream>>>(data, W_cond, b_cond, W_ap, b_ap, W_av, W_gnn,
                                           h_it, x_lin, e_it);
    k_pool<<<BB, 256, 0, stream>>>(e_it, h_it, h_sys);
    k_route<<<1, 64, 0, stream>>>(h_sys, W_r, b_r, gumbel, pi_soft, pi_t);
    k_mixed<<<NN / 4, 256, 0, stream>>>(e_base, lr_u, lr_v, pi_t, x_lin,
                                        att_i, att_j, att_em_i, att_em_j, mixed, s_i, s_j);
    k_topk<<<4096, 256, 0, stream>>>(mixed, tkv, tki);
    k_gat<<<BNROWS / 4, 256, 0, stream>>>(x_lin, s_i, s_j, tkv, tki, b_gnn, gnn_pre);
    k_stats<<<64, 256, 0, stream>>>(gnn_pre, stats);
    k_bn1<<<BNROWS * DD / 256, 256, 0, stream>>>(gnn_pre, stats, bn1_g, bn1_b, net, out_pre);
    k_stats<<<64, 256, 0, stream>>>(out_pre, stats + 128);
    k_head<<<BNROWS / 4, 256, 0, stream>>>(out_pre, stats + 128, bno_g, bno_b, W_out, b_out, out0);
}

// Round 2
// 442.195 us; speedup vs baseline: 2.0872x; 2.0872x over previous
//
#include <hip/hip_runtime.h>
#include <math.h>

#define BB 32
#define NN 1024
#define FF 10
#define DD 64
#define MM 4
#define RR 8
#define KK 20
#define BNROWS (BB*NN)   // 32768

// ---- workspace layout (float offsets) ----
#define OFF_HIT   0ull           // h_it   [B,N,D]  2097152
#define OFF_XLIN  2097152ull     // x_lin  [B,N,D]  2097152
#define OFF_EIT   4194304ull     // e_it   [B,N]    32768
#define OFF_PIT   4227072ull     // pi_t   [B,M]    128
#define OFF_MIXED 4227200ull     // mixed  [B,N,D]  2097152
#define OFF_SI    6324352ull     // s_i    [B,N]    32768
#define OFF_SJ    6357120ull     // s_j    [B,N]    32768
#define OFF_TKV   6389888ull     // topk_vals [B,N,K] 655360
#define OFF_TKI   7045248ull     // topk_idx  [B,N,K] 655360 (ints)
#define OFF_GNN   7700608ull     // gnn_pre [B,N,D] 2097152
#define OFF_OUTP  9797760ull     // out_pre [B,N,D] 2097152
#define OFF_STAT  11894912ull    // stats: 256 floats
#define OFF_SC    (OFF_STAT + 256ull)  // score chunks

__device__ __forceinline__ float wave_sum(float v) {
    #pragma unroll
    for (int off = 32; off; off >>= 1) v += __shfl_xor(v, off);
    return v;
}
__device__ __forceinline__ float wave_max(float v) {
    #pragma unroll
    for (int off = 32; off; off >>= 1) v = fmaxf(v, __shfl_xor(v, off));
    return v;
}

// ---------------- K0: zero stats ----------------
__global__ void k_zero(float* p) { p[threadIdx.x] = 0.f; }

// ---------------- K1a: per-row h_it, x_lin, e_it ----------------
__global__ __launch_bounds__(256) void k_rows(
    const float* __restrict__ data, const float* __restrict__ W_cond,
    const float* __restrict__ b_cond, const float* __restrict__ W_ap,
    const float* __restrict__ b_ap, const float* __restrict__ W_av,
    const float* __restrict__ W_gnn,
    float* __restrict__ h_it, float* __restrict__ x_lin, float* __restrict__ e_it)
{
    int w = threadIdx.x >> 6, lane = threadIdx.x & 63;
    int r = blockIdx.x * 4 + w;               // row in [0, B*N)
    const float* dr = data + r * FF;
    float df[FF];
    #pragma unroll
    for (int f = 0; f < FF; f++) df[f] = dr[f];
    float h = b_cond[lane], x = 0.f;
    #pragma unroll
    for (int f = 0; f < FF; f++) {
        h = fmaf(df[f], W_cond[f * DD + lane], h);
        x = fmaf(df[f], W_gnn[f * DD + lane], x);
    }
    h_it[r * DD + lane] = h;
    x_lin[r * DD + lane] = x;
    float acc = b_ap[lane];
    #pragma unroll
    for (int e2 = 0; e2 < DD; e2++)
        acc = fmaf(__shfl(h, e2), W_ap[e2 * DD + lane], acc);
    float lr = acc > 0.f ? acc : 0.2f * acc;
    float ep = wave_sum(lr * W_av[lane]);
    if (lane == 0) e_it[r] = ep;
}

// ---------------- K1b: per-b softmax over N + weighted pool ----------------
__global__ __launch_bounds__(256) void k_pool(
    const float* __restrict__ e_it, const float* __restrict__ h_it,
    float* __restrict__ h_sys)
{
    int b = blockIdx.x, t = threadIdx.x, w = t >> 6, lane = t & 63;
    __shared__ float sbeta[NN];
    __shared__ float red[4];
    __shared__ float part[4][DD];
    float v[4]; float mx = -INFINITY;
    #pragma unroll
    for (int i = 0; i < 4; i++) { v[i] = e_it[b * NN + t + i * 256]; mx = fmaxf(mx, v[i]); }
    mx = wave_max(mx);
    if (lane == 0) red[w] = mx;
    __syncthreads();
    mx = fmaxf(fmaxf(red[0], red[1]), fmaxf(red[2], red[3]));
    float s = 0.f;
    #pragma unroll
    for (int i = 0; i < 4; i++) { v[i] = expf(v[i] - mx); s += v[i]; }
    s = wave_sum(s);
    __syncthreads();
    if (lane == 0) red[w] = s;
    __syncthreads();
    s = red[0] + red[1] + red[2] + red[3];
    #pragma unroll
    for (int i = 0; i < 4; i++) sbeta[t + i * 256] = v[i] / s;
    __syncthreads();
    float acc = 0.f;
    for (int n = w * 256; n < w * 256 + 256; n++)
        acc = fmaf(sbeta[n], h_it[(b * NN + n) * DD + lane], acc);
    part[w][lane] = acc;
    __syncthreads();
    if (w == 0)
        h_sys[b * DD + lane] = part[0][lane] + part[1][lane] + part[2][lane] + part[3][lane];
}

// ---------------- K2: routing ----------------
__global__ void k_route(const float* __restrict__ h_sys, const float* __restrict__ W_r,
                        const float* __restrict__ b_r, const float* __restrict__ gumbel,
                        float* __restrict__ pi_soft, float* __restrict__ pi_t)
{
    int b = threadIdx.x;
    if (b >= BB) return;
    float lg[MM];
    #pragma unroll
    for (int m = 0; m < MM; m++) {
        float a = b_r[m] + gumbel[b * MM + m];
        for (int d = 0; d < DD; d++) a = fmaf(h_sys[b * DD + d], W_r[d * MM + m], a);
        lg[m] = a;
    }
    float mx = fmaxf(fmaxf(lg[0], lg[1]), fmaxf(lg[2], lg[3]));
    float s = 0.f, p[MM];
    #pragma unroll
    for (int m = 0; m < MM; m++) { p[m] = expf(lg[m] - mx); s += p[m]; }
    #pragma unroll
    for (int m = 0; m < MM; m++) { p[m] /= s; pi_soft[b * MM + m] = p[m]; }
    int i1 = 0; float v1 = p[0];
    #pragma unroll
    for (int m = 1; m < MM; m++) if (p[m] > v1) { v1 = p[m]; i1 = m; }
    int i2 = -1; float v2 = -1.f;
    #pragma unroll
    for (int m = 0; m < MM; m++) if (m != i1 && p[m] > v2) { v2 = p[m]; i2 = m; }
    float norm = fmaxf(v1 + v2, 1e-12f);
    #pragma unroll
    for (int m = 0; m < MM; m++)
        pi_t[b * MM + m] = (m == i1 ? v1 : (m == i2 ? v2 : 0.f)) / norm;
}

// ---------------- K3: mixed embeddings + s_i/s_j (wave per row) ----------------
__global__ __launch_bounds__(256) void k_mixed(
    const float* __restrict__ e_base, const float* __restrict__ lr_u,
    const float* __restrict__ lr_v, const float* __restrict__ pi_t,
    const float* __restrict__ x_lin,
    const float* __restrict__ att_i, const float* __restrict__ att_j,
    const float* __restrict__ att_em_i, const float* __restrict__ att_em_j,
    float* __restrict__ mixed, float* __restrict__ s_i, float* __restrict__ s_j)
{
    int w = threadIdx.x >> 6, lane = threadIdx.x & 63;
    int r = blockIdx.x * 4 + w;
    int b = r >> 10, n = r & 1023;
    float LR[MM];
    #pragma unroll
    for (int m = 0; m < MM; m++) {
        float a = 0.f;
        #pragma unroll
        for (int rr = 0; rr < RR; rr++)
            a = fmaf(lr_u[(m * NN + n) * RR + rr], lr_v[(m * RR + rr) * DD + lane], a);
        LR[m] = a;
    }
    float eb = e_base[n * DD + lane];
    float mx = 0.f;
    #pragma unroll
    for (int m = 0; m < MM; m++) mx = fmaf(pi_t[b * MM + m], eb + LR[m], mx);
    mixed[(size_t)r * DD + lane] = mx;
    float x = x_lin[(size_t)r * DD + lane];
    float r1 = wave_sum(x * att_i[lane] + mx * att_em_i[lane]);
    float r2 = wave_sum(x * att_j[lane] + mx * att_em_j[lane]);
    if (lane == 0) { s_i[r] = r1; s_j[r] = r2; }
}

// ---------------- K4a: score GEMM chunk (scores = mixed mixed^T) ----------------
// grid: c*128 blocks; block computes 64i x 128j tile for one b in chunk.
__global__ __launch_bounds__(256) void k_score(
    const float* __restrict__ mixed_chunk, float* __restrict__ sc)
{
    __shared__ float As[64 * 68];
    __shared__ float Bs[64 * 132];
    int t = threadIdx.x;
    int bb = blockIdx.x >> 7;
    int rr = blockIdx.x & 127;
    int it = rr >> 3, jt = rr & 7;
    int i0 = it * 64, j0 = jt * 128;
    const float* mb = mixed_chunk + (size_t)bb * NN * DD;

    // stage A (64 rows, transposed to As[d][i], stride 68)
    #pragma unroll
    for (int c = 0; c < 4; c++) {
        int id = t + c * 256;            // 0..1023
        int i = id >> 4, q = id & 15;
        const float4 v = *(const float4*)(mb + (size_t)(i0 + i) * DD + q * 4);
        As[(q * 4 + 0) * 68 + i] = v.x;
        As[(q * 4 + 1) * 68 + i] = v.y;
        As[(q * 4 + 2) * 68 + i] = v.z;
        As[(q * 4 + 3) * 68 + i] = v.w;
    }
    // stage B (128 rows, transposed to Bs[d][j], stride 132)
    #pragma unroll
    for (int c = 0; c < 8; c++) {
        int id = t + c * 256;            // 0..2047
        int j = id >> 4, q = id & 15;
        const float4 v = *(const float4*)(mb + (size_t)(j0 + j) * DD + q * 4);
        Bs[(q * 4 + 0) * 132 + j] = v.x;
        Bs[(q * 4 + 1) * 132 + j] = v.y;
        Bs[(q * 4 + 2) * 132 + j] = v.z;
        Bs[(q * 4 + 3) * 132 + j] = v.w;
    }
    __syncthreads();

    int tx = t & 15, ty = t >> 4;        // tx: 8 j's, ty: 4 i's
    float acc[4][8];
    #pragma unroll
    for (int a = 0; a < 4; a++)
        #pragma unroll
        for (int bj = 0; bj < 8; bj++) acc[a][bj] = 0.f;

    #pragma unroll 4
    for (int d = 0; d < 64; d++) {
        float4 a4 = *(const float4*)&As[d * 68 + ty * 4];
        float4 b0 = *(const float4*)&Bs[d * 132 + tx * 8];
        float4 b1 = *(const float4*)&Bs[d * 132 + tx * 8 + 4];
        float av[4] = {a4.x, a4.y, a4.z, a4.w};
        float bv[8] = {b0.x, b0.y, b0.z, b0.w, b1.x, b1.y, b1.z, b1.w};
        #pragma unroll
        for (int a = 0; a < 4; a++)
            #pragma unroll
            for (int bj = 0; bj < 8; bj++)
                acc[a][bj] = fmaf(av[a], bv[bj], acc[a][bj]);
    }

    float* out = sc + ((size_t)bb * NN + i0 + ty * 4) * NN + j0 + tx * 8;
    #pragma unroll
    for (int a = 0; a < 4; a++) {
        float4 o0 = {acc[a][0], acc[a][1], acc[a][2], acc[a][3]};
        float4 o1 = {acc[a][4], acc[a][5], acc[a][6], acc[a][7]};
        *(float4*)(out + (size_t)a * NN) = o0;
        *(float4*)(out + (size_t)a * NN + 4) = o1;
    }
}

// ---------------- K4b: top-20 selection from materialized rows ----------------
// wave per row; slot s of lane l -> j = (s>>2)*256 + l*4 + (s&3)
__global__ __launch_bounds__(256) void k_select(
    const float* __restrict__ sc, int b0,
    float* __restrict__ tkv, int* __restrict__ tki)
{
    int w = threadIdx.x >> 6, lane = threadIdx.x & 63;
    int lr = blockIdx.x * 4 + w;                 // local row within chunk
    const float* row = sc + (size_t)lr * NN;
    float s[16];
    #pragma unroll
    for (int c = 0; c < 4; c++) {
        float4 v = *(const float4*)(row + c * 256 + lane * 4);
        s[c * 4 + 0] = v.x; s[c * 4 + 1] = v.y; s[c * 4 + 2] = v.z; s[c * 4 + 3] = v.w;
    }
    int gr = b0 * NN + lr;                       // global row

    float bv = s[0]; int bs = 0;
    #pragma unroll
    for (int i = 1; i < 16; i++) if (s[i] > bv) { bv = s[i]; bs = i; }
    float myv = 0.f; int myj = 0;
    for (int k = 0; k < KK; k++) {
        float m = wave_max(bv);
        unsigned long long ball = __ballot(bv == m);
        int winner = (int)__builtin_ctzll(ball);
        int wslot = __shfl(bs, winner);
        int j = (wslot >> 2) * 256 + winner * 4 + (wslot & 3);
        if (lane == k) { myv = m; myj = j; }
        bool win = (lane == winner);
        #pragma unroll
        for (int i = 0; i < 16; i++)
            if (win && i == wslot) s[i] = -INFINITY;
        if (win) {
            bv = s[0]; bs = 0;
            #pragma unroll
            for (int i = 1; i < 16; i++) if (s[i] > bv) { bv = s[i]; bs = i; }
        }
    }
    if (lane < KK) { tkv[(size_t)gr * KK + lane] = myv; tki[(size_t)gr * KK + lane] = myj; }
}

// ---------------- K5: GAT attention + aggregation ----------------
__global__ __launch_bounds__(256) void k_gat(
    const float* __restrict__ x_lin, const float* __restrict__ s_i,
    const float* __restrict__ s_j, const float* __restrict__ tkv,
    const int* __restrict__ tki, const float* __restrict__ b_gnn,
    float* __restrict__ gnn_pre)
{
    int w = threadIdx.x >> 6, lane = threadIdx.x & 63;
    int r = blockIdx.x * 4 + w;
    int b = r >> 10, n = r & 1023;
    float vk = -INFINITY; int ik = 0;
    if (lane < KK) { vk = tkv[r * KK + lane]; ik = tki[r * KK + lane]; }
    float m1 = wave_max(vk);
    float ek = (lane < KK) ? expf(vk - m1) : 0.f;
    float s1v = wave_sum(ek);
    float wk = ek / s1v;
    float si = s_i[r], sjn = s_j[r];
    float a = -INFINITY;
    if (lane < KK) {
        float sjk = s_j[(b << 10) + ik];
        float t2 = si + sjk;
        a = (ik == n) ? -INFINITY : (t2 > 0.f ? t2 : 0.2f * t2);
    }
    float ts = si + sjn;
    float aself = ts > 0.f ? ts : 0.2f * ts;
    float am = wave_max(fmaxf(a, aself));
    float ea = (lane < KK && a != -INFINITY) ? expf(a - am) : 0.f;
    float es = expf(aself - am);
    float ssum = wave_sum(ea) + es;
    float wnb = (ea / ssum) * wk;
    float wself = es / ssum;
    float acc = b_gnn[lane] + wself * x_lin[r * DD + lane];
    for (int k = 0; k < KK; k++) {
        int jk = __shfl(ik, k);
        float wv = __shfl(wnb, k);
        acc = fmaf(wv, x_lin[((b << 10) + jk) * DD + lane], acc);
    }
    gnn_pre[r * DD + lane] = acc;
}

// ---------------- K6: per-channel sum / sumsq ----------------
__global__ __launch_bounds__(256) void k_stats(const float* __restrict__ src, float* __restrict__ sums)
{
    int w = threadIdx.x >> 6, lane = threadIdx.x & 63;
    __shared__ float ps[4][DD], pq[4][DD];
    float s = 0.f, q = 0.f;
    int base = blockIdx.x * 512;
    for (int i = w; i < 512; i += 4) {
        float v = src[(size_t)(base + i) * DD + lane];
        s += v; q = fmaf(v, v, q);
    }
    ps[w][lane] = s; pq[w][lane] = q;
    __syncthreads();
    if (w == 0) {
        s = ps[0][lane] + ps[1][lane] + ps[2][lane] + ps[3][lane];
        q = pq[0][lane] + pq[1][lane] + pq[2][lane] + pq[3][lane];
        atomicAdd(&sums[lane], s);
        atomicAdd(&sums[DD + lane], q);
    }
}

// ---------------- K7: bn1 + relu + embed multiply ----------------
__global__ __launch_bounds__(256) void k_bn1(
    const float* __restrict__ gnn_pre, const float* __restrict__ stats,
    const float* __restrict__ gamma, const float* __restrict__ beta,
    const float* __restrict__ net, float* __restrict__ out_pre)
{
    int e = blockIdx.x * 256 + threadIdx.x;
    int d = e & 63, r = e >> 6, n = r & 1023;
    float mean = stats[d] * (1.0f / BNROWS);
    float var = stats[DD + d] * (1.0f / BNROWS) - mean * mean;
    float rs = rsqrtf(var + 1e-5f);
    float y = (gnn_pre[e] - mean) * rs * gamma[d] + beta[d];
    y = y > 0.f ? y : 0.f;
    out_pre[e] = y * net[n * DD + d];
}

// ---------------- K8: bn_out + relu + head ----------------
__global__ __launch_bounds__(256) void k_head(
    const float* __restrict__ out_pre, const float* __restrict__ stats,
    const float* __restrict__ gamma, const float* __restrict__ beta,
    const float* __restrict__ W_out, const float* __restrict__ b_out,
    float* __restrict__ out)
{
    int w = threadIdx.x >> 6, lane = threadIdx.x & 63;
    int r = blockIdx.x * 4 + w;
    float mean = stats[lane] * (1.0f / BNROWS);
    float var = stats[DD + lane] * (1.0f / BNROWS) - mean * mean;
    float rs = rsqrtf(var + 1e-5f);
    float y = (out_pre[(size_t)r * DD + lane] - mean) * rs * gamma[lane] + beta[lane];
    y = y > 0.f ? y : 0.f;
    float p = wave_sum(y * W_out[lane]);
    if (lane == 0) out[r] = p + b_out[0];
}

extern "C" void kernel_launch(void* const* d_in, const int* in_sizes, int n_in,
                              void* d_out, int out_size, void* d_ws, size_t ws_size,
                              hipStream_t stream)
{
    const float* data     = (const float*)d_in[0];
    const float* gumbel   = (const float*)d_in[1];
    const float* W_cond   = (const float*)d_in[2];
    const float* b_cond   = (const float*)d_in[3];
    const float* W_ap     = (const float*)d_in[4];
    const float* b_ap     = (const float*)d_in[5];
    const float* W_av     = (const float*)d_in[6];
    const float* W_r      = (const float*)d_in[7];
    const float* b_r      = (const float*)d_in[8];
    const float* e_base   = (const float*)d_in[9];
    const float* lr_u     = (const float*)d_in[10];
    const float* lr_v     = (const float*)d_in[11];
    const float* W_gnn    = (const float*)d_in[12];
    const float* att_i    = (const float*)d_in[13];
    const float* att_j    = (const float*)d_in[14];
    const float* att_em_i = (const float*)d_in[15];
    const float* att_em_j = (const float*)d_in[16];
    const float* b_gnn    = (const float*)d_in[17];
    const float* bn1_g    = (const float*)d_in[18];
    const float* bn1_b    = (const float*)d_in[19];
    const float* net      = (const float*)d_in[20];
    const float* bno_g    = (const float*)d_in[21];
    const float* bno_b    = (const float*)d_in[22];
    const float* W_out    = (const float*)d_in[23];
    const float* b_out    = (const float*)d_in[24];

    float* ws = (float*)d_ws;
    float* h_it   = ws + OFF_HIT;
    float* x_lin  = ws + OFF_XLIN;
    float* e_it   = ws + OFF_EIT;
    float* pi_t   = ws + OFF_PIT;
    float* mixed  = ws + OFF_MIXED;
    float* s_i    = ws + OFF_SI;
    float* s_j    = ws + OFF_SJ;
    float* tkv    = ws + OFF_TKV;
    int*   tki    = (int*)(ws + OFF_TKI);
    float* gnn_pre = ws + OFF_GNN;
    float* out_pre = ws + OFF_OUTP;
    float* stats   = ws + OFF_STAT;

    float* out0    = (float*)d_out;
    float* h_sys   = out0 + BB * NN;              // 32768
    float* pi_soft = out0 + BB * NN + BB * DD;    // 34816

    k_zero<<<1, 256, 0, stream>>>(stats);
    k_rows<<<BNROWS / 4, 256, 0, stream>>>(data, W_cond, b_cond, W_ap, b_ap, W_av, W_gnn,
                                           h_it, x_lin, e_it);
    k_pool<<<BB, 256, 0, stream>>>(e_it, h_it, h_sys);
    k_route<<<1, 64, 0, stream>>>(h_sys, W_r, b_r, gumbel, pi_soft, pi_t);
    k_mixed<<<BNROWS / 4, 256, 0, stream>>>(e_base, lr_u, lr_v, pi_t, x_lin,
                                            att_i, att_j, att_em_i, att_em_j, mixed, s_i, s_j);

    // ---- chunked score GEMM + selection ----
    size_t ws_floats = ws_size / 4;
    size_t avail = ws_floats > OFF_SC ? ws_floats - OFF_SC : 0;
    int cb = (int)(avail / (size_t)(NN * NN));
    if (cb > BB) cb = BB;
    float* sc = ws + OFF_SC;
    if (cb < 1) { cb = 2; sc = h_it; }   // h_it dead after k_pool; 2 b's = exactly its 8MB
    for (int b0 = 0; b0 < BB; b0 += cb) {
        int c = (BB - b0) < cb ? (BB - b0) : cb;
        k_score<<<c * 128, 256, 0, stream>>>(mixed + (size_t)b0 * NN * DD, sc);
        k_select<<<c * 256, 256, 0, stream>>>(sc, b0, tkv, tki);
    }

    k_gat<<<BNROWS / 4, 256, 0, stream>>>(x_lin, s_i, s_j, tkv, tki, b_gnn, gnn_pre);
    k_stats<<<64, 256, 0, stream>>>(gnn_pre, stats);
    k_bn1<<<BNROWS * DD / 256, 256, 0, stream>>>(gnn_pre, stats, bn1_g, bn1_b, net, out_pre);
    k_stats<<<64, 256, 0, stream>>>(out_pre, stats + 128);
    k_head<<<BNROWS / 4, 256, 0, stream>>>(out_pre, stats + 128, bno_g, bno_b, W_out, b_out, out0);
}

// Round 3
// 358.641 us; speedup vs baseline: 2.5734x; 1.2330x over previous
//
#include <hip/hip_runtime.h>
#include <math.h>

#define BB 32
#define NN 1024
#define FF 10
#define DD 64
#define MM 4
#define RR 8
#define KK 20
#define BNROWS (BB*NN)   // 32768

// ---- workspace layout (float offsets) ----
#define OFF_HIT   0ull           // h_it   [B,N,D]  2097152
#define OFF_XLIN  2097152ull     // x_lin  [B,N,D]  2097152
#define OFF_EIT   4194304ull     // e_it   [B,N]    32768
#define OFF_PIT   4227072ull     // pi_t   [B,M]    128
#define OFF_MIXED 4227200ull     // mixed  [B,N,D]  2097152
#define OFF_SI    6324352ull     // s_i    [B,N]    32768
#define OFF_SJ    6357120ull     // s_j    [B,N]    32768
#define OFF_TKV   6389888ull     // topk_vals [B,N,K] 655360
#define OFF_TKI   7045248ull     // topk_idx  [B,N,K] 655360 (ints)
#define OFF_GNN   7700608ull     // gnn_pre [B,N,D] 2097152
#define OFF_OUTP  9797760ull     // out_pre [B,N,D] 2097152
#define OFF_STAT  11894912ull    // stats: 256 floats
#define OFF_SC    (OFF_STAT + 256ull)  // score chunks

__device__ __forceinline__ float wave_sum(float v) {
    #pragma unroll
    for (int off = 32; off; off >>= 1) v += __shfl_xor(v, off);
    return v;
}
__device__ __forceinline__ float wave_max(float v) {
    #pragma unroll
    for (int off = 32; off; off >>= 1) v = fmaxf(v, __shfl_xor(v, off));
    return v;
}

// DPP wave-max over 64 lanes for uint32; returns uniform max (via lane 63).
__device__ __forceinline__ unsigned int dpp_wave_max_u32(unsigned int x) {
    unsigned int t;
    t = (unsigned)__builtin_amdgcn_update_dpp(0, (int)x, 0x111, 0xF, 0xF, true); // row_shr:1
    x = x > t ? x : t;
    t = (unsigned)__builtin_amdgcn_update_dpp(0, (int)x, 0x112, 0xF, 0xF, true); // row_shr:2
    x = x > t ? x : t;
    t = (unsigned)__builtin_amdgcn_update_dpp(0, (int)x, 0x114, 0xF, 0xF, true); // row_shr:4
    x = x > t ? x : t;
    t = (unsigned)__builtin_amdgcn_update_dpp(0, (int)x, 0x118, 0xF, 0xF, true); // row_shr:8
    x = x > t ? x : t;
    t = (unsigned)__builtin_amdgcn_update_dpp(0, (int)x, 0x142, 0xF, 0xF, true); // row_bcast:15
    x = x > t ? x : t;
    t = (unsigned)__builtin_amdgcn_update_dpp(0, (int)x, 0x143, 0xF, 0xF, true); // row_bcast:31
    x = x > t ? x : t;
    return (unsigned)__builtin_amdgcn_readlane((int)x, 63);
}

// ---------------- K1a: per-row h_it, x_lin, e_it (+ stats zero) ----------------
__global__ __launch_bounds__(256) void k_rows(
    const float* __restrict__ data, const float* __restrict__ W_cond,
    const float* __restrict__ b_cond, const float* __restrict__ W_ap,
    const float* __restrict__ b_ap, const float* __restrict__ W_av,
    const float* __restrict__ W_gnn,
    float* __restrict__ h_it, float* __restrict__ x_lin, float* __restrict__ e_it,
    float* __restrict__ stats)
{
    if (blockIdx.x == 0) stats[threadIdx.x] = 0.f;   // zero 256 stat floats
    int w = threadIdx.x >> 6, lane = threadIdx.x & 63;
    int r = blockIdx.x * 4 + w;               // row in [0, B*N)
    const float* dr = data + r * FF;
    float df[FF];
    #pragma unroll
    for (int f = 0; f < FF; f++) df[f] = dr[f];
    float h = b_cond[lane], x = 0.f;
    #pragma unroll
    for (int f = 0; f < FF; f++) {
        h = fmaf(df[f], W_cond[f * DD + lane], h);
        x = fmaf(df[f], W_gnn[f * DD + lane], x);
    }
    h_it[r * DD + lane] = h;
    x_lin[r * DD + lane] = x;
    float acc = b_ap[lane];
    #pragma unroll
    for (int e2 = 0; e2 < DD; e2++)
        acc = fmaf(__shfl(h, e2), W_ap[e2 * DD + lane], acc);
    float lr = acc > 0.f ? acc : 0.2f * acc;
    float ep = wave_sum(lr * W_av[lane]);
    if (lane == 0) e_it[r] = ep;
}

// ---------------- K1b: per-b softmax over N + weighted pool ----------------
__global__ __launch_bounds__(256) void k_pool(
    const float* __restrict__ e_it, const float* __restrict__ h_it,
    float* __restrict__ h_sys)
{
    int b = blockIdx.x, t = threadIdx.x, w = t >> 6, lane = t & 63;
    __shared__ float sbeta[NN];
    __shared__ float red[4];
    __shared__ float part[4][DD];
    float v[4]; float mx = -INFINITY;
    #pragma unroll
    for (int i = 0; i < 4; i++) { v[i] = e_it[b * NN + t + i * 256]; mx = fmaxf(mx, v[i]); }
    mx = wave_max(mx);
    if (lane == 0) red[w] = mx;
    __syncthreads();
    mx = fmaxf(fmaxf(red[0], red[1]), fmaxf(red[2], red[3]));
    float s = 0.f;
    #pragma unroll
    for (int i = 0; i < 4; i++) { v[i] = expf(v[i] - mx); s += v[i]; }
    s = wave_sum(s);
    __syncthreads();
    if (lane == 0) red[w] = s;
    __syncthreads();
    s = red[0] + red[1] + red[2] + red[3];
    #pragma unroll
    for (int i = 0; i < 4; i++) sbeta[t + i * 256] = v[i] / s;
    __syncthreads();
    float acc = 0.f;
    for (int n = w * 256; n < w * 256 + 256; n++)
        acc = fmaf(sbeta[n], h_it[(b * NN + n) * DD + lane], acc);
    part[w][lane] = acc;
    __syncthreads();
    if (w == 0)
        h_sys[b * DD + lane] = part[0][lane] + part[1][lane] + part[2][lane] + part[3][lane];
}

// ---------------- K2: routing ----------------
__global__ void k_route(const float* __restrict__ h_sys, const float* __restrict__ W_r,
                        const float* __restrict__ b_r, const float* __restrict__ gumbel,
                        float* __restrict__ pi_soft, float* __restrict__ pi_t)
{
    int b = threadIdx.x;
    if (b >= BB) return;
    float lg[MM];
    #pragma unroll
    for (int m = 0; m < MM; m++) {
        float a = b_r[m] + gumbel[b * MM + m];
        for (int d = 0; d < DD; d++) a = fmaf(h_sys[b * DD + d], W_r[d * MM + m], a);
        lg[m] = a;
    }
    float mx = fmaxf(fmaxf(lg[0], lg[1]), fmaxf(lg[2], lg[3]));
    float s = 0.f, p[MM];
    #pragma unroll
    for (int m = 0; m < MM; m++) { p[m] = expf(lg[m] - mx); s += p[m]; }
    #pragma unroll
    for (int m = 0; m < MM; m++) { p[m] /= s; pi_soft[b * MM + m] = p[m]; }
    int i1 = 0; float v1 = p[0];
    #pragma unroll
    for (int m = 1; m < MM; m++) if (p[m] > v1) { v1 = p[m]; i1 = m; }
    int i2 = -1; float v2 = -1.f;
    #pragma unroll
    for (int m = 0; m < MM; m++) if (m != i1 && p[m] > v2) { v2 = p[m]; i2 = m; }
    float norm = fmaxf(v1 + v2, 1e-12f);
    #pragma unroll
    for (int m = 0; m < MM; m++)
        pi_t[b * MM + m] = (m == i1 ? v1 : (m == i2 ? v2 : 0.f)) / norm;
}

// ---------------- K3: mixed embeddings + s_i/s_j (wave per row) ----------------
__global__ __launch_bounds__(256) void k_mixed(
    const float* __restrict__ e_base, const float* __restrict__ lr_u,
    const float* __restrict__ lr_v, const float* __restrict__ pi_t,
    const float* __restrict__ x_lin,
    const float* __restrict__ att_i, const float* __restrict__ att_j,
    const float* __restrict__ att_em_i, const float* __restrict__ att_em_j,
    float* __restrict__ mixed, float* __restrict__ s_i, float* __restrict__ s_j)
{
    int w = threadIdx.x >> 6, lane = threadIdx.x & 63;
    int r = blockIdx.x * 4 + w;
    int b = r >> 10, n = r & 1023;
    float LR[MM];
    #pragma unroll
    for (int m = 0; m < MM; m++) {
        float a = 0.f;
        #pragma unroll
        for (int rr = 0; rr < RR; rr++)
            a = fmaf(lr_u[(m * NN + n) * RR + rr], lr_v[(m * RR + rr) * DD + lane], a);
        LR[m] = a;
    }
    float eb = e_base[n * DD + lane];
    float mx = 0.f;
    #pragma unroll
    for (int m = 0; m < MM; m++) mx = fmaf(pi_t[b * MM + m], eb + LR[m], mx);
    mixed[(size_t)r * DD + lane] = mx;
    float x = x_lin[(size_t)r * DD + lane];
    float r1 = wave_sum(x * att_i[lane] + mx * att_em_i[lane]);
    float r2 = wave_sum(x * att_j[lane] + mx * att_em_j[lane]);
    if (lane == 0) { s_i[r] = r1; s_j[r] = r2; }
}

// ---------------- K4a: score GEMM (scores = mixed mixed^T), 128x128 tile ----------------
// grid: c*64 blocks; block computes 128i x 128j for one b. 8x8 microtile/thread.
__global__ __launch_bounds__(256) void k_score(
    const float* __restrict__ mixed_chunk, float* __restrict__ sc)
{
    __shared__ float As[64 * 132];
    __shared__ float Bs[64 * 132];
    int t = threadIdx.x;
    int bb = blockIdx.x >> 6;
    int rr = blockIdx.x & 63;
    int it = rr >> 3, jt = rr & 7;
    int i0 = it * 128, j0 = jt * 128;
    const float* mb = mixed_chunk + (size_t)bb * NN * DD;

    // stage A and B transposed to [d][row], stride 132.
    // mapping: row = (id&15) + (id>>8)*16, q = (id>>4)&15  -> conflict-free writes
    #pragma unroll
    for (int c = 0; c < 8; c++) {
        int id = t + c * 256;                 // 0..2047
        int row = (id & 15) + ((id >> 8) << 4);
        int q = (id >> 4) & 15;
        const float4 va = *(const float4*)(mb + (size_t)(i0 + row) * DD + q * 4);
        As[(q * 4 + 0) * 132 + row] = va.x;
        As[(q * 4 + 1) * 132 + row] = va.y;
        As[(q * 4 + 2) * 132 + row] = va.z;
        As[(q * 4 + 3) * 132 + row] = va.w;
        const float4 vb = *(const float4*)(mb + (size_t)(j0 + row) * DD + q * 4);
        Bs[(q * 4 + 0) * 132 + row] = vb.x;
        Bs[(q * 4 + 1) * 132 + row] = vb.y;
        Bs[(q * 4 + 2) * 132 + row] = vb.z;
        Bs[(q * 4 + 3) * 132 + row] = vb.w;
    }
    __syncthreads();

    int tx = t & 15, ty = t >> 4;            // tx: 8 j's, ty: 8 i's
    float acc[8][8];
    #pragma unroll
    for (int a = 0; a < 8; a++)
        #pragma unroll
        for (int bj = 0; bj < 8; bj++) acc[a][bj] = 0.f;

    #pragma unroll 4
    for (int d = 0; d < 64; d++) {
        float4 a0 = *(const float4*)&As[d * 132 + ty * 8];
        float4 a1 = *(const float4*)&As[d * 132 + ty * 8 + 4];
        float4 b0 = *(const float4*)&Bs[d * 132 + tx * 8];
        float4 b1 = *(const float4*)&Bs[d * 132 + tx * 8 + 4];
        float av[8] = {a0.x, a0.y, a0.z, a0.w, a1.x, a1.y, a1.z, a1.w};
        float bv[8] = {b0.x, b0.y, b0.z, b0.w, b1.x, b1.y, b1.z, b1.w};
        #pragma unroll
        for (int a = 0; a < 8; a++)
            #pragma unroll
            for (int bj = 0; bj < 8; bj++)
                acc[a][bj] = fmaf(av[a], bv[bj], acc[a][bj]);
    }

    float* out = sc + ((size_t)bb * NN + i0 + ty * 8) * NN + j0 + tx * 8;
    #pragma unroll
    for (int a = 0; a < 8; a++) {
        float4 o0 = {acc[a][0], acc[a][1], acc[a][2], acc[a][3]};
        float4 o1 = {acc[a][4], acc[a][5], acc[a][6], acc[a][7]};
        *(float4*)(out + (size_t)a * NN) = o0;
        *(float4*)(out + (size_t)a * NN + 4) = o1;
    }
}

// ---------------- K4b: top-20 selection, packed-key + sorted 4-groups ----------------
// wave per row; slot s of lane l -> j = (s>>2)*256 + l*4 + (s&3)
__global__ __launch_bounds__(256) void k_select(
    const float* __restrict__ sc, int b0,
    float* __restrict__ tkv, int* __restrict__ tki)
{
    int w = threadIdx.x >> 6, lane = threadIdx.x & 63;
    int lr = blockIdx.x * 4 + w;                 // local row within chunk
    const float* row = sc + (size_t)lr * NN;

    // build sortable keys: (sign-flipped bits & ~0xF) | slot
    unsigned int g[4][4];
    #pragma unroll
    for (int c = 0; c < 4; c++) {
        float4 v = *(const float4*)(row + c * 256 + lane * 4);
        float vv[4] = {v.x, v.y, v.z, v.w};
        #pragma unroll
        for (int q = 0; q < 4; q++) {
            unsigned int u = __float_as_uint(vv[q]);
            unsigned int m = ((unsigned int)((int)u >> 31)) | 0x80000000u;
            g[c][q] = ((u ^ m) & 0xFFFFFFF0u) | (unsigned)(c * 4 + q);
        }
    }
    // sort each group of 4 descending (5 comparators)
    #pragma unroll
    for (int c = 0; c < 4; c++) {
        unsigned a0 = g[c][0], a1 = g[c][1], a2 = g[c][2], a3 = g[c][3], hi, lo;
        hi = a0 > a1 ? a0 : a1; lo = a0 > a1 ? a1 : a0; a0 = hi; a1 = lo;
        hi = a2 > a3 ? a2 : a3; lo = a2 > a3 ? a3 : a2; a2 = hi; a3 = lo;
        hi = a0 > a2 ? a0 : a2; lo = a0 > a2 ? a2 : a0; a0 = hi; a2 = lo;
        hi = a1 > a3 ? a1 : a3; lo = a1 > a3 ? a3 : a1; a1 = hi; a3 = lo;
        hi = a1 > a2 ? a1 : a2; lo = a1 > a2 ? a2 : a1; a1 = hi; a2 = lo;
        g[c][0] = a0; g[c][1] = a1; g[c][2] = a2; g[c][3] = a3;
    }
    unsigned head = g[0][0];
    head = g[1][0] > head ? g[1][0] : head;
    head = g[2][0] > head ? g[2][0] : head;
    head = g[3][0] > head ? g[3][0] : head;

    unsigned myk = 0u; int myj = 0;
    #pragma unroll
    for (int k = 0; k < KK; k++) {
        unsigned m = dpp_wave_max_u32(head);         // uniform
        unsigned long long ball = __ballot(head == m);
        int winner = (int)__builtin_ctzll(ball);     // uniform
        int slot = (int)(m & 15u);                   // uniform
        int j = ((slot >> 2) << 8) + winner * 4 + (slot & 3);
        if (lane == k) { myk = m; myj = j; }
        bool iswin = (lane == winner);
        int gi = slot >> 2;                          // uniform -> s_cbranch
        if (gi == 0) {
            g[0][0] = iswin ? g[0][1] : g[0][0];
            g[0][1] = iswin ? g[0][2] : g[0][1];
            g[0][2] = iswin ? g[0][3] : g[0][2];
            g[0][3] = iswin ? 0u : g[0][3];
        } else if (gi == 1) {
            g[1][0] = iswin ? g[1][1] : g[1][0];
            g[1][1] = iswin ? g[1][2] : g[1][1];
            g[1][2] = iswin ? g[1][3] : g[1][2];
            g[1][3] = iswin ? 0u : g[1][3];
        } else if (gi == 2) {
            g[2][0] = iswin ? g[2][1] : g[2][0];
            g[2][1] = iswin ? g[2][2] : g[2][1];
            g[2][2] = iswin ? g[2][3] : g[2][2];
            g[2][3] = iswin ? 0u : g[2][3];
        } else {
            g[3][0] = iswin ? g[3][1] : g[3][0];
            g[3][1] = iswin ? g[3][2] : g[3][1];
            g[3][2] = iswin ? g[3][3] : g[3][2];
            g[3][3] = iswin ? 0u : g[3][3];
        }
        head = g[0][0];
        head = g[1][0] > head ? g[1][0] : head;
        head = g[2][0] > head ? g[2][0] : head;
        head = g[3][0] > head ? g[3][0] : head;
    }
    if (lane < KK) {
        int gr = b0 * NN + lr;
        unsigned kk = myk & 0xFFFFFFF0u;
        unsigned u = (kk & 0x80000000u) ? (kk ^ 0x80000000u) : ~kk;
        tkv[(size_t)gr * KK + lane] = __uint_as_float(u);
        tki[(size_t)gr * KK + lane] = myj;
    }
}

// ---------------- K5: GAT attention + aggregation ----------------
__global__ __launch_bounds__(256) void k_gat(
    const float* __restrict__ x_lin, const float* __restrict__ s_i,
    const float* __restrict__ s_j, const float* __restrict__ tkv,
    const int* __restrict__ tki, const float* __restrict__ b_gnn,
    float* __restrict__ gnn_pre)
{
    int w = threadIdx.x >> 6, lane = threadIdx.x & 63;
    int r = blockIdx.x * 4 + w;
    int b = r >> 10, n = r & 1023;
    float vk = -INFINITY; int ik = 0;
    if (lane < KK) { vk = tkv[r * KK + lane]; ik = tki[r * KK + lane]; }
    float m1 = wave_max(vk);
    float ek = (lane < KK) ? expf(vk - m1) : 0.f;
    float s1v = wave_sum(ek);
    float wk = ek / s1v;
    float si = s_i[r], sjn = s_j[r];
    float a = -INFINITY;
    if (lane < KK) {
        float sjk = s_j[(b << 10) + ik];
        float t2 = si + sjk;
        a = (ik == n) ? -INFINITY : (t2 > 0.f ? t2 : 0.2f * t2);
    }
    float ts = si + sjn;
    float aself = ts > 0.f ? ts : 0.2f * ts;
    float am = wave_max(fmaxf(a, aself));
    float ea = (lane < KK && a != -INFINITY) ? expf(a - am) : 0.f;
    float es = expf(aself - am);
    float ssum = wave_sum(ea) + es;
    float wnb = (ea / ssum) * wk;
    float wself = es / ssum;
    float acc = b_gnn[lane] + wself * x_lin[r * DD + lane];
    for (int k = 0; k < KK; k++) {
        int jk = __shfl(ik, k);
        float wv = __shfl(wnb, k);
        acc = fmaf(wv, x_lin[((b << 10) + jk) * DD + lane], acc);
    }
    gnn_pre[r * DD + lane] = acc;
}

// ---------------- K6: per-channel sum / sumsq ----------------
__global__ __launch_bounds__(256) void k_stats(const float* __restrict__ src, float* __restrict__ sums)
{
    int w = threadIdx.x >> 6, lane = threadIdx.x & 63;
    __shared__ float ps[4][DD], pq[4][DD];
    float s = 0.f, q = 0.f;
    int base = blockIdx.x * 512;
    for (int i = w; i < 512; i += 4) {
        float v = src[(size_t)(base + i) * DD + lane];
        s += v; q = fmaf(v, v, q);
    }
    ps[w][lane] = s; pq[w][lane] = q;
    __syncthreads();
    if (w == 0) {
        s = ps[0][lane] + ps[1][lane] + ps[2][lane] + ps[3][lane];
        q = pq[0][lane] + pq[1][lane] + pq[2][lane] + pq[3][lane];
        atomicAdd(&sums[lane], s);
        atomicAdd(&sums[DD + lane], q);
    }
}

// ---------------- K7: bn1 + relu + embed multiply ----------------
__global__ __launch_bounds__(256) void k_bn1(
    const float* __restrict__ gnn_pre, const float* __restrict__ stats,
    const float* __restrict__ gamma, const float* __restrict__ beta,
    const float* __restrict__ net, float* __restrict__ out_pre)
{
    int e = blockIdx.x * 256 + threadIdx.x;
    int d = e & 63, r = e >> 6, n = r & 1023;
    float mean = stats[d] * (1.0f / BNROWS);
    float var = stats[DD + d] * (1.0f / BNROWS) - mean * mean;
    float rs = rsqrtf(var + 1e-5f);
    float y = (gnn_pre[e] - mean) * rs * gamma[d] + beta[d];
    y = y > 0.f ? y : 0.f;
    out_pre[e] = y * net[n * DD + d];
}

// ---------------- K8: bn_out + relu + head ----------------
__global__ __launch_bounds__(256) void k_head(
    const float* __restrict__ out_pre, const float* __restrict__ stats,
    const float* __restrict__ gamma, const float* __restrict__ beta,
    const float* __restrict__ W_out, const float* __restrict__ b_out,
    float* __restrict__ out)
{
    int w = threadIdx.x >> 6, lane = threadIdx.x & 63;
    int r = blockIdx.x * 4 + w;
    float mean = stats[lane] * (1.0f / BNROWS);
    float var = stats[DD + lane] * (1.0f / BNROWS) - mean * mean;
    float rs = rsqrtf(var + 1e-5f);
    float y = (out_pre[(size_t)r * DD + lane] - mean) * rs * gamma[lane] + beta[lane];
    y = y > 0.f ? y : 0.f;
    float p = wave_sum(y * W_out[lane]);
    if (lane == 0) out[r] = p + b_out[0];
}

extern "C" void kernel_launch(void* const* d_in, const int* in_sizes, int n_in,
                              void* d_out, int out_size, void* d_ws, size_t ws_size,
                              hipStream_t stream)
{
    const float* data     = (const float*)d_in[0];
    const float* gumbel   = (const float*)d_in[1];
    const float* W_cond   = (const float*)d_in[2];
    const float* b_cond   = (const float*)d_in[3];
    const float* W_ap     = (const float*)d_in[4];
    const float* b_ap     = (const float*)d_in[5];
    const float* W_av     = (const float*)d_in[6];
    const float* W_r      = (const float*)d_in[7];
    const float* b_r      = (const float*)d_in[8];
    const float* e_base   = (const float*)d_in[9];
    const float* lr_u     = (const float*)d_in[10];
    const float* lr_v     = (const float*)d_in[11];
    const float* W_gnn    = (const float*)d_in[12];
    const float* att_i    = (const float*)d_in[13];
    const float* att_j    = (const float*)d_in[14];
    const float* att_em_i = (const float*)d_in[15];
    const float* att_em_j = (const float*)d_in[16];
    const float* b_gnn    = (const float*)d_in[17];
    const float* bn1_g    = (const float*)d_in[18];
    const float* bn1_b    = (const float*)d_in[19];
    const float* net      = (const float*)d_in[20];
    const float* bno_g    = (const float*)d_in[21];
    const float* bno_b    = (const float*)d_in[22];
    const float* W_out    = (const float*)d_in[23];
    const float* b_out    = (const float*)d_in[24];

    float* ws = (float*)d_ws;
    float* h_it   = ws + OFF_HIT;
    float* x_lin  = ws + OFF_XLIN;
    float* e_it   = ws + OFF_EIT;
    float* pi_t   = ws + OFF_PIT;
    float* mixed  = ws + OFF_MIXED;
    float* s_i    = ws + OFF_SI;
    float* s_j    = ws + OFF_SJ;
    float* tkv    = ws + OFF_TKV;
    int*   tki    = (int*)(ws + OFF_TKI);
    float* gnn_pre = ws + OFF_GNN;
    float* out_pre = ws + OFF_OUTP;
    float* stats   = ws + OFF_STAT;

    float* out0    = (float*)d_out;
    float* h_sys   = out0 + BB * NN;              // 32768
    float* pi_soft = out0 + BB * NN + BB * DD;    // 34816

    k_rows<<<BNROWS / 4, 256, 0, stream>>>(data, W_cond, b_cond, W_ap, b_ap, W_av, W_gnn,
                                           h_it, x_lin, e_it, stats);
    k_pool<<<BB, 256, 0, stream>>>(e_it, h_it, h_sys);
    k_route<<<1, 64, 0, stream>>>(h_sys, W_r, b_r, gumbel, pi_soft, pi_t);
    k_mixed<<<BNROWS / 4, 256, 0, stream>>>(e_base, lr_u, lr_v, pi_t, x_lin,
                                            att_i, att_j, att_em_i, att_em_j, mixed, s_i, s_j);

    // ---- chunked score GEMM + selection ----
    size_t ws_floats = ws_size / 4;
    size_t avail = ws_floats > OFF_SC ? ws_floats - OFF_SC : 0;
    int cb = (int)(avail / (size_t)(NN * NN));
    if (cb > BB) cb = BB;
    float* sc = ws + OFF_SC;
    if (cb < 1) { cb = 2; sc = h_it; }   // h_it dead after k_pool; 2 b's = exactly its 8MB
    for (int b0 = 0; b0 < BB; b0 += cb) {
        int c = (BB - b0) < cb ? (BB - b0) : cb;
        k_score<<<c * 64, 256, 0, stream>>>(mixed + (size_t)b0 * NN * DD, sc);
        k_select<<<c * 256, 256, 0, stream>>>(sc, b0, tkv, tki);
    }

    k_gat<<<BNROWS / 4, 256, 0, stream>>>(x_lin, s_i, s_j, tkv, tki, b_gnn, gnn_pre);
    k_stats<<<64, 256, 0, stream>>>(gnn_pre, stats);
    k_bn1<<<BNROWS * DD / 256, 256, 0, stream>>>(gnn_pre, stats, bn1_g, bn1_b, net, out_pre);
    k_stats<<<64, 256, 0, stream>>>(out_pre, stats + 128);
    k_head<<<BNROWS / 4, 256, 0, stream>>>(out_pre, stats + 128, bno_g, bno_b, W_out, b_out, out0);
}

// Round 4
// 345.376 us; speedup vs baseline: 2.6723x; 1.0384x over previous
//
#include <hip/hip_runtime.h>
#include <math.h>

#define BB 32
#define NN 1024
#define FF 10
#define DD 64
#define MM 4
#define RR 8
#define KK 20
#define BNROWS (BB*NN)   // 32768

// ---- workspace layout (float offsets) ----
#define OFF_HIT   0ull           // h_it   [B,N,D]  2097152
#define OFF_XLIN  2097152ull     // x_lin  [B,N,D]  2097152
#define OFF_EIT   4194304ull     // e_it   [B,N]    32768
#define OFF_PIT   4227072ull     // pi_t   [B,M]    128
#define OFF_MIXED 4227200ull     // mixed  [B,N,D]  2097152
#define OFF_SI    6324352ull     // s_i    [B,N]    32768
#define OFF_SJ    6357120ull     // s_j    [B,N]    32768
#define OFF_TKV   6389888ull     // topk_vals [B,N,K] 655360
#define OFF_TKI   7045248ull     // topk_idx  [B,N,K] 655360 (ints)
#define OFF_GNN   7700608ull     // gnn_pre [B,N,D] 2097152
#define OFF_OUTP  9797760ull     // out_pre [B,N,D] 2097152
#define OFF_STAT  11894912ull    // stats 256 + pool num 2048 + pool den 32
#define OFF_SC    (OFF_STAT + 2560ull)  // score chunks

__device__ __forceinline__ float wave_sum(float v) {
    #pragma unroll
    for (int off = 32; off; off >>= 1) v += __shfl_xor(v, off);
    return v;
}
__device__ __forceinline__ float wave_max(float v) {
    #pragma unroll
    for (int off = 32; off; off >>= 1) v = fmaxf(v, __shfl_xor(v, off));
    return v;
}

// DPP wave-max over 64 lanes for uint32; returns uniform max (via lane 63).
__device__ __forceinline__ unsigned int dpp_wave_max_u32(unsigned int x) {
    unsigned int t;
    t = (unsigned)__builtin_amdgcn_update_dpp(0, (int)x, 0x111, 0xF, 0xF, true); // row_shr:1
    x = x > t ? x : t;
    t = (unsigned)__builtin_amdgcn_update_dpp(0, (int)x, 0x112, 0xF, 0xF, true); // row_shr:2
    x = x > t ? x : t;
    t = (unsigned)__builtin_amdgcn_update_dpp(0, (int)x, 0x114, 0xF, 0xF, true); // row_shr:4
    x = x > t ? x : t;
    t = (unsigned)__builtin_amdgcn_update_dpp(0, (int)x, 0x118, 0xF, 0xF, true); // row_shr:8
    x = x > t ? x : t;
    t = (unsigned)__builtin_amdgcn_update_dpp(0, (int)x, 0x142, 0xF, 0xF, true); // row_bcast:15
    x = x > t ? x : t;
    t = (unsigned)__builtin_amdgcn_update_dpp(0, (int)x, 0x143, 0xF, 0xF, true); // row_bcast:31
    x = x > t ? x : t;
    return (unsigned)__builtin_amdgcn_readlane((int)x, 63);
}

// ---------------- K1a: per-row h_it, x_lin, e_it (+ zero accum buffers) ----------------
__global__ __launch_bounds__(256) void k_rows(
    const float* __restrict__ data, const float* __restrict__ W_cond,
    const float* __restrict__ b_cond, const float* __restrict__ W_ap,
    const float* __restrict__ b_ap, const float* __restrict__ W_av,
    const float* __restrict__ W_gnn,
    float* __restrict__ h_it, float* __restrict__ x_lin, float* __restrict__ e_it,
    float* __restrict__ stats)
{
    if (blockIdx.x < 10) {
        int idx = blockIdx.x * 256 + threadIdx.x;
        if (idx < 2336) stats[idx] = 0.f;    // stats(256) + num(2048) + den(32)
    }
    int w = threadIdx.x >> 6, lane = threadIdx.x & 63;
    int r = blockIdx.x * 4 + w;               // row in [0, B*N)
    const float* dr = data + r * FF;
    float df[FF];
    #pragma unroll
    for (int f = 0; f < FF; f++) df[f] = dr[f];
    float h = b_cond[lane], x = 0.f;
    #pragma unroll
    for (int f = 0; f < FF; f++) {
        h = fmaf(df[f], W_cond[f * DD + lane], h);
        x = fmaf(df[f], W_gnn[f * DD + lane], x);
    }
    h_it[r * DD + lane] = h;
    x_lin[r * DD + lane] = x;
    float acc = b_ap[lane];
    #pragma unroll
    for (int e2 = 0; e2 < DD; e2++)
        acc = fmaf(__shfl(h, e2), W_ap[e2 * DD + lane], acc);
    float lr = acc > 0.f ? acc : 0.2f * acc;
    float ep = wave_sum(lr * W_av[lane]);
    if (lane == 0) e_it[r] = ep;
}

// ---------------- K1b: parallel pool partials (no max shift; |e| << 80) ----------------
__global__ __launch_bounds__(256) void k_pool2(
    const float* __restrict__ e_it, const float* __restrict__ h_it,
    float* __restrict__ num, float* __restrict__ den)
{
    int w = threadIdx.x >> 6, lane = threadIdx.x & 63;
    int b = blockIdx.x >> 3, ch = blockIdx.x & 7;
    int base = b * NN + ch * 128 + w * 32;
    float acc = 0.f, dn = 0.f;
    #pragma unroll 4
    for (int i = 0; i < 32; i++) {
        float e = e_it[base + i];
        float wgt = expf(e);
        acc = fmaf(wgt, h_it[(size_t)(base + i) * DD + lane], acc);
        dn += wgt;
    }
    __shared__ float pa[4][DD];
    __shared__ float pd[4];
    pa[w][lane] = acc;
    if (lane == 0) pd[w] = dn;
    __syncthreads();
    if (w == 0) {
        float s = pa[0][lane] + pa[1][lane] + pa[2][lane] + pa[3][lane];
        atomicAdd(&num[b * DD + lane], s);
        if (lane == 0) atomicAdd(&den[b], pd[0] + pd[1] + pd[2] + pd[3]);
    }
}

// ---------------- K2: routing + h_sys normalize ----------------
__global__ void k_route(const float* __restrict__ num, const float* __restrict__ den,
                        const float* __restrict__ W_r, const float* __restrict__ b_r,
                        const float* __restrict__ gumbel,
                        float* __restrict__ h_sys, float* __restrict__ pi_soft,
                        float* __restrict__ pi_t)
{
    int tid = threadIdx.x;
    for (int i = tid; i < BB * DD; i += 256)
        h_sys[i] = num[i] / den[i >> 6];
    if (tid >= BB) return;
    int b = tid;
    float inv = 1.0f / den[b];
    float lg[MM];
    #pragma unroll
    for (int m = 0; m < MM; m++) lg[m] = b_r[m] + gumbel[b * MM + m];
    for (int d = 0; d < DD; d++) {
        float hv = num[b * DD + d] * inv;
        #pragma unroll
        for (int m = 0; m < MM; m++) lg[m] = fmaf(hv, W_r[d * MM + m], lg[m]);
    }
    float mx = fmaxf(fmaxf(lg[0], lg[1]), fmaxf(lg[2], lg[3]));
    float s = 0.f, p[MM];
    #pragma unroll
    for (int m = 0; m < MM; m++) { p[m] = expf(lg[m] - mx); s += p[m]; }
    #pragma unroll
    for (int m = 0; m < MM; m++) { p[m] /= s; pi_soft[b * MM + m] = p[m]; }
    int i1 = 0; float v1 = p[0];
    #pragma unroll
    for (int m = 1; m < MM; m++) if (p[m] > v1) { v1 = p[m]; i1 = m; }
    int i2 = -1; float v2 = -1.f;
    #pragma unroll
    for (int m = 0; m < MM; m++) if (m != i1 && p[m] > v2) { v2 = p[m]; i2 = m; }
    float norm = fmaxf(v1 + v2, 1e-12f);
    #pragma unroll
    for (int m = 0; m < MM; m++)
        pi_t[b * MM + m] = (m == i1 ? v1 : (m == i2 ? v2 : 0.f)) / norm;
}

// ---------------- K3: mixed embeddings + s_i/s_j (wave per row) ----------------
__global__ __launch_bounds__(256) void k_mixed(
    const float* __restrict__ e_base, const float* __restrict__ lr_u,
    const float* __restrict__ lr_v, const float* __restrict__ pi_t,
    const float* __restrict__ x_lin,
    const float* __restrict__ att_i, const float* __restrict__ att_j,
    const float* __restrict__ att_em_i, const float* __restrict__ att_em_j,
    float* __restrict__ mixed, float* __restrict__ s_i, float* __restrict__ s_j)
{
    int w = threadIdx.x >> 6, lane = threadIdx.x & 63;
    int r = blockIdx.x * 4 + w;
    int b = r >> 10, n = r & 1023;
    float LR[MM];
    #pragma unroll
    for (int m = 0; m < MM; m++) {
        float a = 0.f;
        #pragma unroll
        for (int rr = 0; rr < RR; rr++)
            a = fmaf(lr_u[(m * NN + n) * RR + rr], lr_v[(m * RR + rr) * DD + lane], a);
        LR[m] = a;
    }
    float eb = e_base[n * DD + lane];
    float mx = 0.f;
    #pragma unroll
    for (int m = 0; m < MM; m++) mx = fmaf(pi_t[b * MM + m], eb + LR[m], mx);
    mixed[(size_t)r * DD + lane] = mx;
    float x = x_lin[(size_t)r * DD + lane];
    float r1 = wave_sum(x * att_i[lane] + mx * att_em_i[lane]);
    float r2 = wave_sum(x * att_j[lane] + mx * att_em_j[lane]);
    if (lane == 0) { s_i[r] = r1; s_j[r] = r2; }
}

// ---------------- K4a: score GEMM, 128x128 tile, K split in two 32-stages ----------------
// LDS 33.8 KB -> 4 blocks/CU. Same per-thread fmaf order as before (bit-identical).
__global__ __launch_bounds__(256) void k_score(
    const float* __restrict__ mixed_chunk, float* __restrict__ sc)
{
    __shared__ float As[32 * 132];
    __shared__ float Bs[32 * 132];
    int t = threadIdx.x;
    int bb = blockIdx.x >> 6;
    int rr = blockIdx.x & 63;
    int it = rr >> 3, jt = rr & 7;
    int i0 = it * 128, j0 = jt * 128;
    const float* mb = mixed_chunk + (size_t)bb * NN * DD;

    int tx = t & 15, ty = t >> 4;            // tx: 8 j's, ty: 8 i's
    float acc[8][8];
    #pragma unroll
    for (int a = 0; a < 8; a++)
        #pragma unroll
        for (int bj = 0; bj < 8; bj++) acc[a][bj] = 0.f;

    for (int hh = 0; hh < 2; hh++) {
        if (hh) __syncthreads();
        // stage half: 128 rows x 32 d, transposed to [d][row], stride 132
        #pragma unroll
        for (int c = 0; c < 4; c++) {
            int id = t + c * 256;                 // 0..1023
            int row = (id & 15) | ((id >> 7) << 4);
            int q = (id >> 4) & 7;
            const float4 va = *(const float4*)(mb + (size_t)(i0 + row) * DD + hh * 32 + q * 4);
            As[(q * 4 + 0) * 132 + row] = va.x;
            As[(q * 4 + 1) * 132 + row] = va.y;
            As[(q * 4 + 2) * 132 + row] = va.z;
            As[(q * 4 + 3) * 132 + row] = va.w;
            const float4 vb = *(const float4*)(mb + (size_t)(j0 + row) * DD + hh * 32 + q * 4);
            Bs[(q * 4 + 0) * 132 + row] = vb.x;
            Bs[(q * 4 + 1) * 132 + row] = vb.y;
            Bs[(q * 4 + 2) * 132 + row] = vb.z;
            Bs[(q * 4 + 3) * 132 + row] = vb.w;
        }
        __syncthreads();
        #pragma unroll 4
        for (int d = 0; d < 32; d++) {
            float4 a0 = *(const float4*)&As[d * 132 + ty * 8];
            float4 a1 = *(const float4*)&As[d * 132 + ty * 8 + 4];
            float4 b0 = *(const float4*)&Bs[d * 132 + tx * 8];
            float4 b1 = *(const float4*)&Bs[d * 132 + tx * 8 + 4];
            float av[8] = {a0.x, a0.y, a0.z, a0.w, a1.x, a1.y, a1.z, a1.w};
            float bv[8] = {b0.x, b0.y, b0.z, b0.w, b1.x, b1.y, b1.z, b1.w};
            #pragma unroll
            for (int a = 0; a < 8; a++)
                #pragma unroll
                for (int bj = 0; bj < 8; bj++)
                    acc[a][bj] = fmaf(av[a], bv[bj], acc[a][bj]);
        }
    }

    float* out = sc + ((size_t)bb * NN + i0 + ty * 8) * NN + j0 + tx * 8;
    #pragma unroll
    for (int a = 0; a < 8; a++) {
        float4 o0 = {acc[a][0], acc[a][1], acc[a][2], acc[a][3]};
        float4 o1 = {acc[a][4], acc[a][5], acc[a][6], acc[a][7]};
        *(float4*)(out + (size_t)a * NN) = o0;
        *(float4*)(out + (size_t)a * NN + 4) = o1;
    }
}

// ---------------- K4b: top-20 selection, full-precision keys + slot regs ----------------
// wave per row; slot s of lane l -> j = (s>>2)*256 + l*4 + (s&3)
__global__ __launch_bounds__(256) void k_select(
    const float* __restrict__ sc, int b0,
    float* __restrict__ tkv, int* __restrict__ tki)
{
    int w = threadIdx.x >> 6, lane = threadIdx.x & 63;
    int lr = blockIdx.x * 4 + w;                 // local row within chunk
    const float* row = sc + (size_t)lr * NN;

    unsigned gk[4][4];   // monotone-transformed full-precision keys, sorted desc
    int gs[4][4];        // global slot (0..15) carried alongside
    #pragma unroll
    for (int c = 0; c < 4; c++) {
        float4 v = *(const float4*)(row + c * 256 + lane * 4);
        float vv[4] = {v.x, v.y, v.z, v.w};
        #pragma unroll
        for (int q = 0; q < 4; q++) {
            unsigned u = __float_as_uint(vv[q]);
            unsigned msk = ((unsigned)((int)u >> 31)) | 0x80000000u;
            gk[c][q] = u ^ msk;
            gs[c][q] = c * 4 + q;
        }
        // sort 4 desc (5 comparators), stable (keeps lower slot first on ties)
        #define CMPSWAP(x, y) { \
            bool sw = gk[c][x] < gk[c][y]; \
            unsigned ka = gk[c][x], kb2 = gk[c][y]; int sa = gs[c][x], sb = gs[c][y]; \
            gk[c][x] = sw ? kb2 : ka; gk[c][y] = sw ? ka : kb2; \
            gs[c][x] = sw ? sb : sa; gs[c][y] = sw ? sa : sb; }
        CMPSWAP(0, 1) CMPSWAP(2, 3) CMPSWAP(0, 2) CMPSWAP(1, 3) CMPSWAP(1, 2)
        #undef CMPSWAP
    }
    unsigned head; int hs;
    {
        unsigned h01 = gk[0][0]; int s01 = gs[0][0];
        if (gk[1][0] > h01) { h01 = gk[1][0]; s01 = gs[1][0]; }
        unsigned h23 = gk[2][0]; int s23 = gs[2][0];
        if (gk[3][0] > h23) { h23 = gk[3][0]; s23 = gs[3][0]; }
        head = h01; hs = s01;
        if (h23 > head) { head = h23; hs = s23; }
    }

    float myv = 0.f; int myj = 0;
    #pragma unroll
    for (int k = 0; k < KK; k++) {
        unsigned m = dpp_wave_max_u32(head);         // uniform
        unsigned long long ball = __ballot(head == m);
        int winner = (int)__builtin_ctzll(ball);     // uniform (lowest lane on tie)
        int slotw = __shfl(hs, winner);              // winner's slot
        int j = ((slotw >> 2) << 8) + winner * 4 + (slotw & 3);
        unsigned um = (m & 0x80000000u) ? (m ^ 0x80000000u) : ~m;
        if (lane == k) { myv = __uint_as_float(um); myj = j; }
        bool iswin = (lane == winner);
        int gi = slotw >> 2;                         // uniform -> scalar branch
        #define POPG(c) { \
            gk[c][0] = iswin ? gk[c][1] : gk[c][0]; gs[c][0] = iswin ? gs[c][1] : gs[c][0]; \
            gk[c][1] = iswin ? gk[c][2] : gk[c][1]; gs[c][1] = iswin ? gs[c][2] : gs[c][1]; \
            gk[c][2] = iswin ? gk[c][3] : gk[c][2]; gs[c][2] = iswin ? gs[c][3] : gs[c][2]; \
            gk[c][3] = iswin ? 0u : gk[c][3]; }
        if (gi == 0) { POPG(0) } else if (gi == 1) { POPG(1) }
        else if (gi == 2) { POPG(2) } else { POPG(3) }
        #undef POPG
        unsigned h01 = gk[0][0]; int s01 = gs[0][0];
        if (gk[1][0] > h01) { h01 = gk[1][0]; s01 = gs[1][0]; }
        unsigned h23 = gk[2][0]; int s23 = gs[2][0];
        if (gk[3][0] > h23) { h23 = gk[3][0]; s23 = gs[3][0]; }
        head = h01; hs = s01;
        if (h23 > head) { head = h23; hs = s23; }
    }
    if (lane < KK) {
        int gr = b0 * NN + lr;
        tkv[(size_t)gr * KK + lane] = myv;
        tki[(size_t)gr * KK + lane] = myj;
    }
}

// ---------------- K5: GAT attention + aggregation ----------------
__global__ __launch_bounds__(256) void k_gat(
    const float* __restrict__ x_lin, const float* __restrict__ s_i,
    const float* __restrict__ s_j, const float* __restrict__ tkv,
    const int* __restrict__ tki, const float* __restrict__ b_gnn,
    float* __restrict__ gnn_pre)
{
    int w = threadIdx.x >> 6, lane = threadIdx.x & 63;
    int r = blockIdx.x * 4 + w;
    int b = r >> 10, n = r & 1023;
    float vk = -INFINITY; int ik = 0;
    if (lane < KK) { vk = tkv[r * KK + lane]; ik = tki[r * KK + lane]; }
    float m1 = wave_max(vk);
    float ek = (lane < KK) ? expf(vk - m1) : 0.f;
    float s1v = wave_sum(ek);
    float wk = ek / s1v;
    float si = s_i[r], sjn = s_j[r];
    float a = -INFINITY;
    if (lane < KK) {
        float sjk = s_j[(b << 10) + ik];
        float t2 = si + sjk;
        a = (ik == n) ? -INFINITY : (t2 > 0.f ? t2 : 0.2f * t2);
    }
    float ts = si + sjn;
    float aself = ts > 0.f ? ts : 0.2f * ts;
    float am = wave_max(fmaxf(a, aself));
    float ea = (lane < KK && a != -INFINITY) ? expf(a - am) : 0.f;
    float es = expf(aself - am);
    float ssum = wave_sum(ea) + es;
    float wnb = (ea / ssum) * wk;
    float wself = es / ssum;
    float acc = b_gnn[lane] + wself * x_lin[r * DD + lane];
    #pragma unroll
    for (int k = 0; k < KK; k++) {
        int jk = __shfl(ik, k);
        float wv = __shfl(wnb, k);
        acc = fmaf(wv, x_lin[((b << 10) + jk) * DD + lane], acc);
    }
    gnn_pre[r * DD + lane] = acc;
}

// ---------------- K6: per-channel sum / sumsq over gnn_pre ----------------
__global__ __launch_bounds__(256) void k_stats(const float* __restrict__ src, float* __restrict__ sums)
{
    int w = threadIdx.x >> 6, lane = threadIdx.x & 63;
    __shared__ float ps[4][DD], pq[4][DD];
    float s = 0.f, q = 0.f;
    int base = blockIdx.x * 128;
    for (int i = w; i < 128; i += 4) {
        float v = src[(size_t)(base + i) * DD + lane];
        s += v; q = fmaf(v, v, q);
    }
    ps[w][lane] = s; pq[w][lane] = q;
    __syncthreads();
    if (w == 0) {
        s = ps[0][lane] + ps[1][lane] + ps[2][lane] + ps[3][lane];
        q = pq[0][lane] + pq[1][lane] + pq[2][lane] + pq[3][lane];
        atomicAdd(&sums[lane], s);
        atomicAdd(&sums[DD + lane], q);
    }
}

// ---------------- K7: bn1 + relu + embed multiply (+ bno stats partials) ----------------
__global__ __launch_bounds__(256) void k_bn1(
    const float* __restrict__ gnn_pre, float* __restrict__ stats,
    const float* __restrict__ gamma, const float* __restrict__ beta,
    const float* __restrict__ net, float* __restrict__ out_pre)
{
    int tid = threadIdx.x;
    int d0 = (tid & 15) * 4;
    float mean4[4], rs4[4], bt4[4];
    #pragma unroll
    for (int k = 0; k < 4; k++) {
        float mu = stats[d0 + k] * (1.0f / BNROWS);
        float var = stats[64 + d0 + k] * (1.0f / BNROWS) - mu * mu;
        mean4[k] = mu;
        rs4[k] = rsqrtf(var + 1e-5f) * gamma[d0 + k];
        bt4[k] = beta[d0 + k];
    }
    float s4[4] = {0, 0, 0, 0}, q4[4] = {0, 0, 0, 0};
    size_t base4 = (size_t)blockIdx.x * 2048;     // float4 units (128 rows/block)
    #pragma unroll
    for (int i = 0; i < 8; i++) {
        size_t f4 = base4 + (size_t)i * 256 + tid;
        float4 v = ((const float4*)gnn_pre)[f4];
        int n = ((int)(f4 >> 4)) & 1023;
        float4 nv = ((const float4*)net)[(size_t)n * 16 + (tid & 15)];
        float vv[4] = {v.x, v.y, v.z, v.w};
        float nn2[4] = {nv.x, nv.y, nv.z, nv.w};
        float ov[4];
        #pragma unroll
        for (int k = 0; k < 4; k++) {
            float y = (vv[k] - mean4[k]) * rs4[k] + bt4[k];
            y = y > 0.f ? y : 0.f;
            float o = y * nn2[k];
            ov[k] = o;
            s4[k] += o;
            q4[k] = fmaf(o, o, q4[k]);
        }
        float4 o4 = {ov[0], ov[1], ov[2], ov[3]};
        ((float4*)out_pre)[f4] = o4;
    }
    __shared__ float4 ls[256], lq[256];
    ls[tid] = make_float4(s4[0], s4[1], s4[2], s4[3]);
    lq[tid] = make_float4(q4[0], q4[1], q4[2], q4[3]);
    __syncthreads();
    if (tid < 16) {
        float4 S = ls[tid], Q = lq[tid];
        #pragma unroll
        for (int rr = 1; rr < 16; rr++) {
            float4 a = ls[tid + 16 * rr], b = lq[tid + 16 * rr];
            S.x += a.x; S.y += a.y; S.z += a.z; S.w += a.w;
            Q.x += b.x; Q.y += b.y; Q.z += b.z; Q.w += b.w;
        }
        atomicAdd(&stats[128 + tid * 4 + 0], S.x);
        atomicAdd(&stats[128 + tid * 4 + 1], S.y);
        atomicAdd(&stats[128 + tid * 4 + 2], S.z);
        atomicAdd(&stats[128 + tid * 4 + 3], S.w);
        atomicAdd(&stats[192 + tid * 4 + 0], Q.x);
        atomicAdd(&stats[192 + tid * 4 + 1], Q.y);
        atomicAdd(&stats[192 + tid * 4 + 2], Q.z);
        atomicAdd(&stats[192 + tid * 4 + 3], Q.w);
    }
}

// ---------------- K8: bn_out + relu + head ----------------
__global__ __launch_bounds__(256) void k_head(
    const float* __restrict__ out_pre, const float* __restrict__ stats,
    const float* __restrict__ gamma, const float* __restrict__ beta,
    const float* __restrict__ W_out, const float* __restrict__ b_out,
    float* __restrict__ out)
{
    int w = threadIdx.x >> 6, lane = threadIdx.x & 63;
    int r = blockIdx.x * 4 + w;
    float mean = stats[lane] * (1.0f / BNROWS);
    float var = stats[DD + lane] * (1.0f / BNROWS) - mean * mean;
    float rs = rsqrtf(var + 1e-5f);
    float y = (out_pre[(size_t)r * DD + lane] - mean) * rs * gamma[lane] + beta[lane];
    y = y > 0.f ? y : 0.f;
    float p = wave_sum(y * W_out[lane]);
    if (lane == 0) out[r] = p + b_out[0];
}

extern "C" void kernel_launch(void* const* d_in, const int* in_sizes, int n_in,
                              void* d_out, int out_size, void* d_ws, size_t ws_size,
                              hipStream_t stream)
{
    const float* data     = (const float*)d_in[0];
    const float* gumbel   = (const float*)d_in[1];
    const float* W_cond   = (const float*)d_in[2];
    const float* b_cond   = (const float*)d_in[3];
    const float* W_ap     = (const float*)d_in[4];
    const float* b_ap     = (const float*)d_in[5];
    const float* W_av     = (const float*)d_in[6];
    const float* W_r      = (const float*)d_in[7];
    const float* b_r      = (const float*)d_in[8];
    const float* e_base   = (const float*)d_in[9];
    const float* lr_u     = (const float*)d_in[10];
    const float* lr_v     = (const float*)d_in[11];
    const float* W_gnn    = (const float*)d_in[12];
    const float* att_i    = (const float*)d_in[13];
    const float* att_j    = (const float*)d_in[14];
    const float* att_em_i = (const float*)d_in[15];
    const float* att_em_j = (const float*)d_in[16];
    const float* b_gnn    = (const float*)d_in[17];
    const float* bn1_g    = (const float*)d_in[18];
    const float* bn1_b    = (const float*)d_in[19];
    const float* net      = (const float*)d_in[20];
    const float* bno_g    = (const float*)d_in[21];
    const float* bno_b    = (const float*)d_in[22];
    const float* W_out    = (const float*)d_in[23];
    const float* b_out    = (const float*)d_in[24];

    float* ws = (float*)d_ws;
    float* h_it   = ws + OFF_HIT;
    float* x_lin  = ws + OFF_XLIN;
    float* e_it   = ws + OFF_EIT;
    float* pi_t   = ws + OFF_PIT;
    float* mixed  = ws + OFF_MIXED;
    float* s_i    = ws + OFF_SI;
    float* s_j    = ws + OFF_SJ;
    float* tkv    = ws + OFF_TKV;
    int*   tki    = (int*)(ws + OFF_TKI);
    float* gnn_pre = ws + OFF_GNN;
    float* out_pre = ws + OFF_OUTP;
    float* stats   = ws + OFF_STAT;          // 256 stats
    float* pnum    = stats + 256;            // 2048
    float* pden    = stats + 2304;           // 32

    float* out0    = (float*)d_out;
    float* h_sys   = out0 + BB * NN;              // 32768
    float* pi_soft = out0 + BB * NN + BB * DD;    // 34816

    k_rows<<<BNROWS / 4, 256, 0, stream>>>(data, W_cond, b_cond, W_ap, b_ap, W_av, W_gnn,
                                           h_it, x_lin, e_it, stats);
    k_pool2<<<BB * 8, 256, 0, stream>>>(e_it, h_it, pnum, pden);
    k_route<<<1, 256, 0, stream>>>(pnum, pden, W_r, b_r, gumbel, h_sys, pi_soft, pi_t);
    k_mixed<<<BNROWS / 4, 256, 0, stream>>>(e_base, lr_u, lr_v, pi_t, x_lin,
                                            att_i, att_j, att_em_i, att_em_j, mixed, s_i, s_j);

    // ---- chunked score GEMM + selection ----
    size_t ws_floats = ws_size / 4;
    size_t avail = ws_floats > OFF_SC ? ws_floats - OFF_SC : 0;
    int cb = (int)(avail / (size_t)(NN * NN));
    if (cb > BB) cb = BB;
    float* sc = ws + OFF_SC;
    if (cb < 1) { cb = 2; sc = h_it; }   // h_it dead after k_pool2; 2 b's fit in its 8MB
    for (int b0 = 0; b0 < BB; b0 += cb) {
        int c = (BB - b0) < cb ? (BB - b0) : cb;
        k_score<<<c * 64, 256, 0, stream>>>(mixed + (size_t)b0 * NN * DD, sc);
        k_select<<<c * 256, 256, 0, stream>>>(sc, b0, tkv, tki);
    }

    k_gat<<<BNROWS / 4, 256, 0, stream>>>(x_lin, s_i, s_j, tkv, tki, b_gnn, gnn_pre);
    k_stats<<<256, 256, 0, stream>>>(gnn_pre, stats);
    k_bn1<<<256, 256, 0, stream>>>(gnn_pre, stats, bn1_g, bn1_b, net, out_pre);
    k_head<<<BNROWS / 4, 256, 0, stream>>>(out_pre, stats + 128, bno_g, bno_b, W_out, b_out, out0);
}

// Round 5
// 319.801 us; speedup vs baseline: 2.8860x; 1.0800x over previous
//
#include <hip/hip_runtime.h>
#include <math.h>

#define BB 32
#define NN 1024
#define FF 10
#define DD 64
#define MM 4
#define RR 8
#define KK 20
#define BNROWS (BB*NN)   // 32768

// ---- workspace layout (float offsets) ----
#define OFF_HIT   0ull           // h_it   [B,N,D]  2097152
#define OFF_XLIN  2097152ull     // x_lin  [B,N,D]  2097152
#define OFF_EIT   4194304ull     // e_it   [B,N]    32768
#define OFF_PIT   4227072ull     // pi_t   [B,M]    128
#define OFF_MIXED 4227200ull     // mixed  [B,N,D]  2097152
#define OFF_SI    6324352ull     // s_i    [B,N]    32768
#define OFF_SJ    6357120ull     // s_j    [B,N]    32768
#define OFF_GNN   7700608ull     // gnn_pre [B,N,D] 2097152
#define OFF_OUTP  9797760ull     // out_pre [B,N,D] 2097152
#define OFF_STAT  11894912ull    // stats 256 + pool num 2048 + pool den 32
#define OFF_SC    (OFF_STAT + 2560ull)  // score chunks

__device__ __forceinline__ float wave_sum(float v) {
    #pragma unroll
    for (int off = 32; off; off >>= 1) v += __shfl_xor(v, off);
    return v;
}
__device__ __forceinline__ float wave_max(float v) {
    #pragma unroll
    for (int off = 32; off; off >>= 1) v = fmaxf(v, __shfl_xor(v, off));
    return v;
}

// ---------------- K1a: per-row h_it, x_lin, e_it (+ zero accum buffers) ----------------
__global__ __launch_bounds__(256) void k_rows(
    const float* __restrict__ data, const float* __restrict__ W_cond,
    const float* __restrict__ b_cond, const float* __restrict__ W_ap,
    const float* __restrict__ b_ap, const float* __restrict__ W_av,
    const float* __restrict__ W_gnn,
    float* __restrict__ h_it, float* __restrict__ x_lin, float* __restrict__ e_it,
    float* __restrict__ stats)
{
    if (blockIdx.x < 10) {
        int idx = blockIdx.x * 256 + threadIdx.x;
        if (idx < 2336) stats[idx] = 0.f;    // stats(256) + num(2048) + den(32)
    }
    int w = threadIdx.x >> 6, lane = threadIdx.x & 63;
    int r = blockIdx.x * 4 + w;               // row in [0, B*N)
    const float* dr = data + r * FF;
    float df[FF];
    #pragma unroll
    for (int f = 0; f < FF; f++) df[f] = dr[f];
    float h = b_cond[lane], x = 0.f;
    #pragma unroll
    for (int f = 0; f < FF; f++) {
        h = fmaf(df[f], W_cond[f * DD + lane], h);
        x = fmaf(df[f], W_gnn[f * DD + lane], x);
    }
    h_it[r * DD + lane] = h;
    x_lin[r * DD + lane] = x;
    float acc = b_ap[lane];
    #pragma unroll
    for (int e2 = 0; e2 < DD; e2++)
        acc = fmaf(__shfl(h, e2), W_ap[e2 * DD + lane], acc);
    float lr = acc > 0.f ? acc : 0.2f * acc;
    float ep = wave_sum(lr * W_av[lane]);
    if (lane == 0) e_it[r] = ep;
}

// ---------------- K1b: parallel pool partials (no max shift; |e| small) ----------------
__global__ __launch_bounds__(256) void k_pool2(
    const float* __restrict__ e_it, const float* __restrict__ h_it,
    float* __restrict__ num, float* __restrict__ den)
{
    int w = threadIdx.x >> 6, lane = threadIdx.x & 63;
    int b = blockIdx.x >> 3, ch = blockIdx.x & 7;
    int base = b * NN + ch * 128 + w * 32;
    float acc = 0.f, dn = 0.f;
    #pragma unroll 4
    for (int i = 0; i < 32; i++) {
        float e = e_it[base + i];
        float wgt = expf(e);
        acc = fmaf(wgt, h_it[(size_t)(base + i) * DD + lane], acc);
        dn += wgt;
    }
    __shared__ float pa[4][DD];
    __shared__ float pd[4];
    pa[w][lane] = acc;
    if (lane == 0) pd[w] = dn;
    __syncthreads();
    if (w == 0) {
        float s = pa[0][lane] + pa[1][lane] + pa[2][lane] + pa[3][lane];
        atomicAdd(&num[b * DD + lane], s);
        if (lane == 0) atomicAdd(&den[b], pd[0] + pd[1] + pd[2] + pd[3]);
    }
}

// ---------------- K2: routing + h_sys normalize ----------------
__global__ void k_route(const float* __restrict__ num, const float* __restrict__ den,
                        const float* __restrict__ W_r, const float* __restrict__ b_r,
                        const float* __restrict__ gumbel,
                        float* __restrict__ h_sys, float* __restrict__ pi_soft,
                        float* __restrict__ pi_t)
{
    int tid = threadIdx.x;
    for (int i = tid; i < BB * DD; i += 256)
        h_sys[i] = num[i] / den[i >> 6];
    if (tid >= BB) return;
    int b = tid;
    float inv = 1.0f / den[b];
    float lg[MM];
    #pragma unroll
    for (int m = 0; m < MM; m++) lg[m] = b_r[m] + gumbel[b * MM + m];
    for (int d = 0; d < DD; d++) {
        float hv = num[b * DD + d] * inv;
        #pragma unroll
        for (int m = 0; m < MM; m++) lg[m] = fmaf(hv, W_r[d * MM + m], lg[m]);
    }
    float mx = fmaxf(fmaxf(lg[0], lg[1]), fmaxf(lg[2], lg[3]));
    float s = 0.f, p[MM];
    #pragma unroll
    for (int m = 0; m < MM; m++) { p[m] = expf(lg[m] - mx); s += p[m]; }
    #pragma unroll
    for (int m = 0; m < MM; m++) { p[m] /= s; pi_soft[b * MM + m] = p[m]; }
    int i1 = 0; float v1 = p[0];
    #pragma unroll
    for (int m = 1; m < MM; m++) if (p[m] > v1) { v1 = p[m]; i1 = m; }
    int i2 = -1; float v2 = -1.f;
    #pragma unroll
    for (int m = 0; m < MM; m++) if (m != i1 && p[m] > v2) { v2 = p[m]; i2 = m; }
    float norm = fmaxf(v1 + v2, 1e-12f);
    #pragma unroll
    for (int m = 0; m < MM; m++)
        pi_t[b * MM + m] = (m == i1 ? v1 : (m == i2 ? v2 : 0.f)) / norm;
}

// ---------------- K3: mixed embeddings + s_i/s_j (wave per row) ----------------
__global__ __launch_bounds__(256) void k_mixed(
    const float* __restrict__ e_base, const float* __restrict__ lr_u,
    const float* __restrict__ lr_v, const float* __restrict__ pi_t,
    const float* __restrict__ x_lin,
    const float* __restrict__ att_i, const float* __restrict__ att_j,
    const float* __restrict__ att_em_i, const float* __restrict__ att_em_j,
    float* __restrict__ mixed, float* __restrict__ s_i, float* __restrict__ s_j)
{
    int w = threadIdx.x >> 6, lane = threadIdx.x & 63;
    int r = blockIdx.x * 4 + w;
    int b = r >> 10, n = r & 1023;
    float LR[MM];
    #pragma unroll
    for (int m = 0; m < MM; m++) {
        float a = 0.f;
        #pragma unroll
        for (int rr = 0; rr < RR; rr++)
            a = fmaf(lr_u[(m * NN + n) * RR + rr], lr_v[(m * RR + rr) * DD + lane], a);
        LR[m] = a;
    }
    float eb = e_base[n * DD + lane];
    float mx = 0.f;
    #pragma unroll
    for (int m = 0; m < MM; m++) mx = fmaf(pi_t[b * MM + m], eb + LR[m], mx);
    mixed[(size_t)r * DD + lane] = mx;
    float x = x_lin[(size_t)r * DD + lane];
    float r1 = wave_sum(x * att_i[lane] + mx * att_em_i[lane]);
    float r2 = wave_sum(x * att_j[lane] + mx * att_em_j[lane]);
    if (lane == 0) { s_i[r] = r1; s_j[r] = r2; }
}

// ---------------- K4a: score GEMM, 128x128, swizzled conflict-free LDS ----------------
// swz(row) = ((row&4)<<4) | ((row>>3)<<2) | (row&3): b128 reads hit each bank 2x (free)
__global__ __launch_bounds__(256) void k_score(
    const float* __restrict__ mixed_chunk, float* __restrict__ sc)
{
    __shared__ float As[32 * 132];
    __shared__ float Bs[32 * 132];
    int t = threadIdx.x;
    int bb = blockIdx.x >> 6;
    int rr = blockIdx.x & 63;
    int it = rr >> 3, jt = rr & 7;
    int i0 = it * 128, j0 = jt * 128;
    const float* mb = mixed_chunk + (size_t)bb * NN * DD;

    int tx = t & 15, ty = t >> 4;            // tx: 8 j's, ty: 8 i's
    float acc[8][8];
    #pragma unroll
    for (int a = 0; a < 8; a++)
        #pragma unroll
        for (int bj = 0; bj < 8; bj++) acc[a][bj] = 0.f;

    int rowi[4], qi[4], swi[4];
    #pragma unroll
    for (int c = 0; c < 4; c++) {
        int id = t + c * 256;                 // 0..1023
        rowi[c] = (id & 15) | ((id >> 7) << 4);
        qi[c] = (id >> 4) & 7;
        swi[c] = ((rowi[c] & 4) << 4) | ((rowi[c] >> 3) << 2) | (rowi[c] & 3);
    }

    float4 pa[4], pb[4];
    #pragma unroll
    for (int c = 0; c < 4; c++) {            // prefetch half 0
        pa[c] = *(const float4*)(mb + (size_t)(i0 + rowi[c]) * DD + qi[c] * 4);
        pb[c] = *(const float4*)(mb + (size_t)(j0 + rowi[c]) * DD + qi[c] * 4);
    }
    for (int hh = 0; hh < 2; hh++) {
        if (hh) __syncthreads();
        #pragma unroll
        for (int c = 0; c < 4; c++) {
            int pos = qi[c] * 4 * 132 + swi[c];
            As[pos] = pa[c].x; As[pos + 132] = pa[c].y; As[pos + 264] = pa[c].z; As[pos + 396] = pa[c].w;
            Bs[pos] = pb[c].x; Bs[pos + 132] = pb[c].y; Bs[pos + 264] = pb[c].z; Bs[pos + 396] = pb[c].w;
        }
        __syncthreads();
        if (hh == 0) {                        // prefetch half 1 during compute of half 0
            #pragma unroll
            for (int c = 0; c < 4; c++) {
                pa[c] = *(const float4*)(mb + (size_t)(i0 + rowi[c]) * DD + 32 + qi[c] * 4);
                pb[c] = *(const float4*)(mb + (size_t)(j0 + rowi[c]) * DD + 32 + qi[c] * 4);
            }
        }
        #pragma unroll 4
        for (int d = 0; d < 32; d++) {
            float4 a0 = *(const float4*)&As[d * 132 + ty * 4];        // rows ty*8+0..3
            float4 a1 = *(const float4*)&As[d * 132 + 64 + ty * 4];   // rows ty*8+4..7
            float4 b0 = *(const float4*)&Bs[d * 132 + tx * 4];
            float4 b1 = *(const float4*)&Bs[d * 132 + 64 + tx * 4];
            float av[8] = {a0.x, a0.y, a0.z, a0.w, a1.x, a1.y, a1.z, a1.w};
            float bv[8] = {b0.x, b0.y, b0.z, b0.w, b1.x, b1.y, b1.z, b1.w};
            #pragma unroll
            for (int a = 0; a < 8; a++)
                #pragma unroll
                for (int bj = 0; bj < 8; bj++)
                    acc[a][bj] = fmaf(av[a], bv[bj], acc[a][bj]);
        }
    }

    float* out = sc + ((size_t)bb * NN + i0 + ty * 8) * NN + j0 + tx * 8;
    #pragma unroll
    for (int a = 0; a < 8; a++) {
        float4 o0 = {acc[a][0], acc[a][1], acc[a][2], acc[a][3]};
        float4 o1 = {acc[a][4], acc[a][5], acc[a][6], acc[a][7]};
        *(float4*)(out + (size_t)a * NN) = o0;
        *(float4*)(out + (size_t)a * NN + 4) = o1;
    }
}

// ---------------- K4b: fused top-20 selection + GAT ----------------
// wave per row. slot s of lane l -> j = (s>>2)*256 + l*4 + (s&3)
__global__ __launch_bounds__(256) void k_selgat(
    const float* __restrict__ sc, int b0,
    const float* __restrict__ x_lin, const float* __restrict__ s_i,
    const float* __restrict__ s_j, const float* __restrict__ b_gnn,
    float* __restrict__ gnn_pre)
{
    int w = threadIdx.x >> 6, lane = threadIdx.x & 63;
    int lr = blockIdx.x * 4 + w;                 // local row within chunk
    int r = b0 * NN + lr;                        // global row
    int b = r >> 10, n = r & 1023;
    const float* row = sc + (size_t)lr * NN;

    unsigned uk[16];
    #pragma unroll
    for (int c = 0; c < 4; c++) {
        float4 v = *(const float4*)(row + c * 256 + lane * 4);
        float vv[4] = {v.x, v.y, v.z, v.w};
        #pragma unroll
        for (int q = 0; q < 4; q++) {
            unsigned u = __float_as_uint(vv[q]);
            uk[c * 4 + q] = u ^ (((unsigned)((int)u >> 31)) | 0x80000000u);
        }
    }
    // per-lane max
    unsigned mx = uk[0];
    #pragma unroll
    for (int i = 1; i < 16; i++) mx = uk[i] > mx ? uk[i] : mx;
    // bitonic sort-64 (desc) of lane maxima -> tau = 20th largest (<= true 20th value)
    unsigned sv = mx;
    #pragma unroll
    for (int blk = 2; blk <= 64; blk <<= 1) {
        #pragma unroll
        for (int dist = blk >> 1; dist >= 1; dist >>= 1) {
            unsigned pv = (unsigned)__shfl_xor((int)sv, dist);
            bool up = (lane & blk) == 0;
            bool upper = (lane & dist) == 0;
            bool g = sv > pv;
            sv = (((g == upper) == up)) ? sv : pv;
        }
    }
    unsigned tau = (unsigned)__shfl((int)sv, 19);

    // ballot-prefix compact candidates >= tau into LDS
    __shared__ unsigned skey[4][64];
    __shared__ int sjj[4][64];
    int base = 0;
    #pragma unroll
    for (int s = 0; s < 16; s++) {
        bool q = uk[s] >= tau;
        unsigned long long m = __ballot(q);
        if (q) {
            int pos = base + __popcll(m & ((1ull << lane) - 1ull));
            if (pos < 64) {
                skey[w][pos] = uk[s];
                sjj[w][pos] = ((s >> 2) << 8) + lane * 4 + (s & 3);
            }
        }
        base += __popcll(m);
    }
    int C = base;   // >= 20 guaranteed

    float vk = -INFINITY; int ik = 0;
    if (C <= 64) {
        unsigned ck = 0u; int cj = 0x7FFFFFFF;
        if (lane < C) { ck = skey[w][lane]; cj = sjj[w][lane]; }
        if (C <= 32) {
            #pragma unroll
            for (int blk = 2; blk <= 32; blk <<= 1)
                #pragma unroll
                for (int dist = blk >> 1; dist >= 1; dist >>= 1) {
                    unsigned pk = (unsigned)__shfl_xor((int)ck, dist);
                    int pj = __shfl_xor(cj, dist);
                    bool up = (lane & blk) == 0;
                    bool upper = (lane & dist) == 0;
                    bool g = (ck > pk) || (ck == pk && cj < pj);
                    bool keep = ((g == upper) == up);
                    ck = keep ? ck : pk; cj = keep ? cj : pj;
                }
        } else {
            #pragma unroll
            for (int blk = 2; blk <= 64; blk <<= 1)
                #pragma unroll
                for (int dist = blk >> 1; dist >= 1; dist >>= 1) {
                    unsigned pk = (unsigned)__shfl_xor((int)ck, dist);
                    int pj = __shfl_xor(cj, dist);
                    bool up = (lane & blk) == 0;
                    bool upper = (lane & dist) == 0;
                    bool g = (ck > pk) || (ck == pk && cj < pj);
                    bool keep = ((g == upper) == up);
                    ck = keep ? ck : pk; cj = keep ? cj : pj;
                }
        }
        if (lane < KK) {
            unsigned u = (ck & 0x80000000u) ? (ck ^ 0x80000000u) : ~ck;
            vk = __uint_as_float(u);
            ik = cj;
        }
    } else {
        // rare fallback: full 20-round extraction
        for (int k = 0; k < KK; k++) {
            unsigned bm = uk[0]; int bsl = 0;
            #pragma unroll
            for (int i = 1; i < 16; i++) if (uk[i] > bm) { bm = uk[i]; bsl = i; }
            unsigned wm = bm;
            #pragma unroll
            for (int off = 32; off; off >>= 1) {
                unsigned tt = (unsigned)__shfl_xor((int)wm, off);
                wm = tt > wm ? tt : wm;
            }
            unsigned long long ball = __ballot(bm == wm);
            int winner = (int)__builtin_ctzll(ball);
            int slotw = __shfl(bsl, winner);
            int jw = ((slotw >> 2) << 8) + winner * 4 + (slotw & 3);
            unsigned u2 = (wm & 0x80000000u) ? (wm ^ 0x80000000u) : ~wm;
            if (lane == k) { vk = __uint_as_float(u2); ik = jw; }
            if (lane == winner) uk[bsl] = 0u;
        }
    }

    // ---- GAT (former k_gat, operands already in registers) ----
    float m1 = wave_max(vk);
    float ek = (lane < KK) ? expf(vk - m1) : 0.f;
    float s1v = wave_sum(ek);
    float wk = ek / s1v;
    float si = s_i[r], sjn = s_j[r];
    float a = -INFINITY;
    if (lane < KK) {
        float sjk = s_j[(b << 10) + ik];
        float t2 = si + sjk;
        a = (ik == n) ? -INFINITY : (t2 > 0.f ? t2 : 0.2f * t2);
    }
    float ts = si + sjn;
    float aself = ts > 0.f ? ts : 0.2f * ts;
    float am = wave_max(fmaxf(a, aself));
    float ea = (lane < KK && a != -INFINITY) ? expf(a - am) : 0.f;
    float es = expf(aself - am);
    float ssum = wave_sum(ea) + es;
    float wnb = (ea / ssum) * wk;
    float wself = es / ssum;
    float acc = b_gnn[lane] + wself * x_lin[(size_t)r * DD + lane];
    #pragma unroll
    for (int k = 0; k < KK; k++) {
        int jk = __shfl(ik, k);
        float wv = __shfl(wnb, k);
        acc = fmaf(wv, x_lin[((size_t)(b << 10) + jk) * DD + lane], acc);
    }
    gnn_pre[(size_t)r * DD + lane] = acc;
}

// ---------------- K6: per-channel sum / sumsq over gnn_pre ----------------
__global__ __launch_bounds__(256) void k_stats(const float* __restrict__ src, float* __restrict__ sums)
{
    int w = threadIdx.x >> 6, lane = threadIdx.x & 63;
    __shared__ float ps[4][DD], pq[4][DD];
    float s = 0.f, q = 0.f;
    int base = blockIdx.x * 128;
    for (int i = w; i < 128; i += 4) {
        float v = src[(size_t)(base + i) * DD + lane];
        s += v; q = fmaf(v, v, q);
    }
    ps[w][lane] = s; pq[w][lane] = q;
    __syncthreads();
    if (w == 0) {
        s = ps[0][lane] + ps[1][lane] + ps[2][lane] + ps[3][lane];
        q = pq[0][lane] + pq[1][lane] + pq[2][lane] + pq[3][lane];
        atomicAdd(&sums[lane], s);
        atomicAdd(&sums[DD + lane], q);
    }
}

// ---------------- K7: bn1 + relu + embed multiply (+ bno stats partials) ----------------
__global__ __launch_bounds__(256) void k_bn1(
    const float* __restrict__ gnn_pre, float* __restrict__ stats,
    const float* __restrict__ gamma, const float* __restrict__ beta,
    const float* __restrict__ net, float* __restrict__ out_pre)
{
    int tid = threadIdx.x;
    int d0 = (tid & 15) * 4;
    float mean4[4], rs4[4], bt4[4];
    #pragma unroll
    for (int k = 0; k < 4; k++) {
        float mu = stats[d0 + k] * (1.0f / BNROWS);
        float var = stats[64 + d0 + k] * (1.0f / BNROWS) - mu * mu;
        mean4[k] = mu;
        rs4[k] = rsqrtf(var + 1e-5f) * gamma[d0 + k];
        bt4[k] = beta[d0 + k];
    }
    float s4[4] = {0, 0, 0, 0}, q4[4] = {0, 0, 0, 0};
    size_t base4 = (size_t)blockIdx.x * 2048;     // float4 units (128 rows/block)
    #pragma unroll
    for (int i = 0; i < 8; i++) {
        size_t f4 = base4 + (size_t)i * 256 + tid;
        float4 v = ((const float4*)gnn_pre)[f4];
        int n = ((int)(f4 >> 4)) & 1023;
        float4 nv = ((const float4*)net)[(size_t)n * 16 + (tid & 15)];
        float vv[4] = {v.x, v.y, v.z, v.w};
        float nn2[4] = {nv.x, nv.y, nv.z, nv.w};
        float ov[4];
        #pragma unroll
        for (int k = 0; k < 4; k++) {
            float y = (vv[k] - mean4[k]) * rs4[k] + bt4[k];
            y = y > 0.f ? y : 0.f;
            float o = y * nn2[k];
            ov[k] = o;
            s4[k] += o;
            q4[k] = fmaf(o, o, q4[k]);
        }
        float4 o4 = {ov[0], ov[1], ov[2], ov[3]};
        ((float4*)out_pre)[f4] = o4;
    }
    __shared__ float4 ls[256], lq[256];
    ls[tid] = make_float4(s4[0], s4[1], s4[2], s4[3]);
    lq[tid] = make_float4(q4[0], q4[1], q4[2], q4[3]);
    __syncthreads();
    if (tid < 16) {
        float4 S = ls[tid], Q = lq[tid];
        #pragma unroll
        for (int rr = 1; rr < 16; rr++) {
            float4 a = ls[tid + 16 * rr], b = lq[tid + 16 * rr];
            S.x += a.x; S.y += a.y; S.z += a.z; S.w += a.w;
            Q.x += b.x; Q.y += b.y; Q.z += b.z; Q.w += b.w;
        }
        atomicAdd(&stats[128 + tid * 4 + 0], S.x);
        atomicAdd(&stats[128 + tid * 4 + 1], S.y);
        atomicAdd(&stats[128 + tid * 4 + 2], S.z);
        atomicAdd(&stats[128 + tid * 4 + 3], S.w);
        atomicAdd(&stats[192 + tid * 4 + 0], Q.x);
        atomicAdd(&stats[192 + tid * 4 + 1], Q.y);
        atomicAdd(&stats[192 + tid * 4 + 2], Q.z);
        atomicAdd(&stats[192 + tid * 4 + 3], Q.w);
    }
}

// ---------------- K8: bn_out + relu + head ----------------
__global__ __launch_bounds__(256) void k_head(
    const float* __restrict__ out_pre, const float* __restrict__ stats,
    const float* __restrict__ gamma, const float* __restrict__ beta,
    const float* __restrict__ W_out, const float* __restrict__ b_out,
    float* __restrict__ out)
{
    int w = threadIdx.x >> 6, lane = threadIdx.x & 63;
    int r = blockIdx.x * 4 + w;
    float mean = stats[lane] * (1.0f / BNROWS);
    float var = stats[DD + lane] * (1.0f / BNROWS) - mean * mean;
    float rs = rsqrtf(var + 1e-5f);
    float y = (out_pre[(size_t)r * DD + lane] - mean) * rs * gamma[lane] + beta[lane];
    y = y > 0.f ? y : 0.f;
    float p = wave_sum(y * W_out[lane]);
    if (lane == 0) out[r] = p + b_out[0];
}

extern "C" void kernel_launch(void* const* d_in, const int* in_sizes, int n_in,
                              void* d_out, int out_size, void* d_ws, size_t ws_size,
                              hipStream_t stream)
{
    const float* data     = (const float*)d_in[0];
    const float* gumbel   = (const float*)d_in[1];
    const float* W_cond   = (const float*)d_in[2];
    const float* b_cond   = (const float*)d_in[3];
    const float* W_ap     = (const float*)d_in[4];
    const float* b_ap     = (const float*)d_in[5];
    const float* W_av     = (const float*)d_in[6];
    const float* W_r      = (const float*)d_in[7];
    const float* b_r      = (const float*)d_in[8];
    const float* e_base   = (const float*)d_in[9];
    const float* lr_u     = (const float*)d_in[10];
    const float* lr_v     = (const float*)d_in[11];
    const float* W_gnn    = (const float*)d_in[12];
    const float* att_i    = (const float*)d_in[13];
    const float* att_j    = (const float*)d_in[14];
    const float* att_em_i = (const float*)d_in[15];
    const float* att_em_j = (const float*)d_in[16];
    const float* b_gnn    = (const float*)d_in[17];
    const float* bn1_g    = (const float*)d_in[18];
    const float* bn1_b    = (const float*)d_in[19];
    const float* net      = (const float*)d_in[20];
    const float* bno_g    = (const float*)d_in[21];
    const float* bno_b    = (const float*)d_in[22];
    const float* W_out    = (const float*)d_in[23];
    const float* b_out    = (const float*)d_in[24];

    float* ws = (float*)d_ws;
    float* h_it   = ws + OFF_HIT;
    float* x_lin  = ws + OFF_XLIN;
    float* e_it   = ws + OFF_EIT;
    float* pi_t   = ws + OFF_PIT;
    float* mixed  = ws + OFF_MIXED;
    float* s_i    = ws + OFF_SI;
    float* s_j    = ws + OFF_SJ;
    float* gnn_pre = ws + OFF_GNN;
    float* out_pre = ws + OFF_OUTP;
    float* stats   = ws + OFF_STAT;          // 256 stats
    float* pnum    = stats + 256;            // 2048
    float* pden    = stats + 2304;           // 32

    float* out0    = (float*)d_out;
    float* h_sys   = out0 + BB * NN;              // 32768
    float* pi_soft = out0 + BB * NN + BB * DD;    // 34816

    k_rows<<<BNROWS / 4, 256, 0, stream>>>(data, W_cond, b_cond, W_ap, b_ap, W_av, W_gnn,
                                           h_it, x_lin, e_it, stats);
    k_pool2<<<BB * 8, 256, 0, stream>>>(e_it, h_it, pnum, pden);
    k_route<<<1, 256, 0, stream>>>(pnum, pden, W_r, b_r, gumbel, h_sys, pi_soft, pi_t);
    k_mixed<<<BNROWS / 4, 256, 0, stream>>>(e_base, lr_u, lr_v, pi_t, x_lin,
                                            att_i, att_j, att_em_i, att_em_j, mixed, s_i, s_j);

    // ---- chunked score GEMM + fused selection/GAT ----
    size_t ws_floats = ws_size / 4;
    size_t avail = ws_floats > OFF_SC ? ws_floats - OFF_SC : 0;
    int cb = (int)(avail / (size_t)(NN * NN));
    if (cb > BB) cb = BB;
    float* sc = ws + OFF_SC;
    if (cb < 1) { cb = 2; sc = h_it; }   // h_it dead after k_pool2; 2 b's fit in its 8MB
    for (int b0 = 0; b0 < BB; b0 += cb) {
        int c = (BB - b0) < cb ? (BB - b0) : cb;
        k_score<<<c * 64, 256, 0, stream>>>(mixed + (size_t)b0 * NN * DD, sc);
        k_selgat<<<c * 256, 256, 0, stream>>>(sc, b0, x_lin, s_i, s_j, b_gnn, gnn_pre);
    }

    k_stats<<<256, 256, 0, stream>>>(gnn_pre, stats);
    k_bn1<<<256, 256, 0, stream>>>(gnn_pre, stats, bn1_g, bn1_b, net, out_pre);
    k_head<<<BNROWS / 4, 256, 0, stream>>>(out_pre, stats + 128, bno_g, bno_b, W_out, b_out, out0);
}